// Round 1
// baseline (352.710 us; speedup 1.0000x reference)
//
#include <hip/hip_runtime.h>
#include <cstdint>
#include <cstddef>

// Problem constants
//  x: (8, 1024, 256) f32 ; Wqk: (256,512) ; bqk: (512) ; bn_gamma/beta: (1024)
//  lepe_w: (256,1,3,3) ; lepe_b: (256)
// Outputs concat: out(8,1024,256) qh(8,8,1024,32) kh(8,8,1024,32)
//                 v_img(8,256,32,32) atten(8,8,1024,1024)

#define OFF_OUT   0
#define OFF_QH    2097152
#define OFF_KH    4194304
#define OFF_VIMG  6291456
#define OFF_ATT   8388608

// ws layout (4-byte units)
#define WS_MQ   0        // 8*8*1024 u32
#define WS_MK   65536
#define WS_TBL  131072   // 1024*128*2 f32 (cos,sin)
#define WS_KV   393216   // 64*32*32 f32
#define WS_KMS  458752   // 64*33 f32

// ---------------- RoPE cos/sin table: tbl[n][j][2] ----------------
__global__ __launch_bounds__(256) void rope_tbl_kernel(float* __restrict__ tbl) {
    int id = blockIdx.x * 256 + threadIdx.x;   // 131072 total
    int j = id & 127, n = id >> 7;
    int hh = n >> 5, ww = n & 31;
    int i = (j < 64) ? j : j - 64;
    float th = powf(10000.0f, -(float)i * (1.0f / 64.0f));
    float pos = (float)((j < 64) ? hh : ww);
    float ang = pos * th;
    tbl[n * 256 + j * 2]     = cosf(ang);
    tbl[n * 256 + j * 2 + 1] = sinf(ang);
}

// ---------------- fused GEMM + BN + LIF + bit-pack ----------------
// grid 256 blocks (4 n-rows each), 512 threads (thread = output channel c)
__global__ __launch_bounds__(512) void qk_lif_kernel(
    const float* __restrict__ x, const float* __restrict__ Wqk,
    const float* __restrict__ bqk, const float* __restrict__ gamma,
    const float* __restrict__ beta, unsigned* __restrict__ mq,
    unsigned* __restrict__ mk)
{
    int t = threadIdx.x;          // channel c in [0,512)
    int n0 = blockIdx.x * 4;
    float acc[32];
    #pragma unroll
    for (int i = 0; i < 32; ++i) acc[i] = 0.f;
    const float* xb = x + n0 * 256;       // x[(b*1024+n0+r)*256 + k]
    #pragma unroll 4
    for (int k = 0; k < 256; ++k) {
        float w = Wqk[k * 512 + t];
        #pragma unroll
        for (int b = 0; b < 8; ++b) {
            #pragma unroll
            for (int r = 0; r < 4; ++r)
                acc[b * 4 + r] = fmaf(xb[b * 262144 + r * 256 + k], w, acc[b * 4 + r]);
        }
    }
    float bb = bqk[t];
    #pragma unroll
    for (int r = 0; r < 4; ++r) {
        int n = n0 + r;
        float g = gamma[n], be = beta[n];
        float v = 0.f;
        #pragma unroll
        for (int b = 0; b < 8; ++b) {
            float val = (acc[b * 4 + r] + bb) * g + be;   // BN over channel dim by n
            v = v + (val - v) * 0.5f;                     // TAU = 2
            bool sp = (v >= 1.0f);
            unsigned long long m = __ballot(sp ? 1 : 0);
            if ((t & 31) == 0) {
                unsigned word = (t & 32) ? (unsigned)(m >> 32) : (unsigned)m;
                unsigned hd = (unsigned)(t >> 5) & 7u;
                unsigned* dst = (t < 256) ? mq : mk;
                dst[b * 8192 + hd * 1024 + n] = word;
            }
            v = sp ? 0.0f : v;
        }
    }
}

// ---------------- atten = 32 + rq + rk + popc(mq & mk) ----------------
// grid 64*(1024/32)=2048 blocks, 256 threads; thread owns 4 columns for 32 rows
__global__ __launch_bounds__(256) void atten_kernel(
    const unsigned* __restrict__ mq, const unsigned* __restrict__ mk,
    float* __restrict__ att)
{
    int t = threadIdx.x;
    int bh = blockIdx.x >> 5;
    int tile = blockIdx.x & 31;
    uint4 mm = ((const uint4*)(mk + bh * 1024))[t];
    float4 rr;
    rr.x = (float)__popc(mm.x); rr.y = (float)__popc(mm.y);
    rr.z = (float)__popc(mm.z); rr.w = (float)__popc(mm.w);
    float* base = att + ((size_t)bh * 1024 + (size_t)tile * 32) * 1024;
    for (int row = 0; row < 32; ++row) {
        unsigned mqw = mq[bh * 1024 + tile * 32 + row];
        float rq = 32.0f + (float)__popc(mqw);
        float4 o;
        o.x = rq + rr.x + (float)__popc(mqw & mm.x);
        o.y = rq + rr.y + (float)__popc(mqw & mm.y);
        o.z = rq + rr.z + (float)__popc(mqw & mm.z);
        o.w = rq + rr.w + (float)__popc(mqw & mm.w);
        ((float4*)(base + (size_t)row * 1024))[t] = o;
    }
}

// ---------------- kmean/S + kv = (k_rope^T @ vh)/1024 per (b,h) ----------------
__global__ __launch_bounds__(256) void kv_kernel(
    const unsigned* __restrict__ mk, const float* __restrict__ x,
    const float* __restrict__ tbl, float* __restrict__ kvws,
    float* __restrict__ kms)
{
    int t = threadIdx.x;
    int bh = blockIdx.x;
    int b = bh >> 3, h = bh & 7;
    __shared__ float part[8][32];
    __shared__ float kmf[33];
    __shared__ float kr[64][36];
    __shared__ float vhs[64][33];
    int d = t & 31, ch = t >> 5;
    int s = 0;
    for (int i = 0; i < 128; ++i)
        s += (mk[bh * 1024 + ch * 128 + i] >> d) & 1u;
    part[ch][d] = (float)s;
    __syncthreads();
    if (t < 32) {
        float cs = 0.f;
        #pragma unroll
        for (int j = 0; j < 8; ++j) cs += part[j][t];
        float km = 1.0f + cs * (1.0f / 1024.0f);
        kmf[t] = km;
        kms[bh * 33 + t] = km;
    }
    __syncthreads();
    if (t == 0) {
        float S = 0.f;
        for (int j = 0; j < 32; ++j) S += kmf[j];
        kms[bh * 33 + 32] = S;
    }
    // kv: thread owns (d-range db..db+3, e)
    float a0 = 0, a1 = 0, a2 = 0, a3 = 0;
    int e = t & 31, db = (t >> 5) * 4;
    for (int c0 = 0; c0 < 1024; c0 += 64) {
        __syncthreads();
        #pragma unroll
        for (int i = 0; i < 8; ++i) {
            int f = t + i * 256;
            int nn = f >> 5, dd = f & 31;
            int n = c0 + nn;
            unsigned w = mk[bh * 1024 + n];
            float kd = 1.0f + (float)((w >> dd) & 1u);
            float ko = 1.0f + (float)((w >> (dd ^ 1)) & 1u);
            const float* cp = tbl + n * 256 + (h * 16 + (dd >> 1)) * 2;
            float cc = cp[0], ss2 = cp[1];
            kr[nn][dd] = (dd & 1) ? (ss2 * ko + cc * kd) : (cc * kd - ss2 * ko);
            vhs[nn][dd] = x[(b * 1024 + n) * 256 + h * 32 + dd];
        }
        __syncthreads();
        #pragma unroll 8
        for (int nn = 0; nn < 64; ++nn) {
            float ve = vhs[nn][e];
            float4 kk = *(const float4*)&kr[nn][db];
            a0 = fmaf(kk.x, ve, a0); a1 = fmaf(kk.y, ve, a1);
            a2 = fmaf(kk.z, ve, a2); a3 = fmaf(kk.w, ve, a3);
        }
    }
    const float inv = 1.0f / 1024.0f;
    kvws[bh * 1024 + (db + 0) * 32 + e] = a0 * inv;
    kvws[bh * 1024 + (db + 1) * 32 + e] = a1 * inv;
    kvws[bh * 1024 + (db + 2) * 32 + e] = a2 * inv;
    kvws[bh * 1024 + (db + 3) * 32 + e] = a3 * inv;
}

// ---------------- out = q_rope@kv * z + lepe ----------------
// grid 64*8=512 blocks, 256 threads: thread = (row r in pass, col e)
__global__ __launch_bounds__(256) void out_kernel(
    const unsigned* __restrict__ mq, const float* __restrict__ x,
    const float* __restrict__ tbl, const float* __restrict__ kvws,
    const float* __restrict__ kms, const float* __restrict__ lw,
    const float* __restrict__ lb, float* __restrict__ out)
{
    int t = threadIdx.x;
    int bi = blockIdx.x;
    int bh = bi >> 3, seg = bi & 7;
    int b = bh >> 3, h = bh & 7;
    __shared__ float kvs[32][33];
    __shared__ float kmf[32];
    __shared__ float Ssh;
    __shared__ float qrs[8][36];
    #pragma unroll
    for (int i = 0; i < 4; ++i) {
        int f = t + i * 256;
        kvs[f >> 5][f & 31] = kvws[bh * 1024 + f];
    }
    if (t < 32) kmf[t] = kms[bh * 33 + t];
    if (t == 0) Ssh = kms[bh * 33 + 32];
    int e = t & 31, r = t >> 5;
    int c = h * 32 + e;
    float w9[9];
    #pragma unroll
    for (int j = 0; j < 9; ++j) w9[j] = lw[c * 9 + j];
    float lbv = lb[c];
    __syncthreads();
    float S = Ssh;
    for (int pass = 0; pass < 16; ++pass) {
        int n = seg * 128 + pass * 8 + r;
        unsigned w = mq[bh * 1024 + n];
        float qd = 1.0f + (float)((w >> e) & 1u);
        float qo = 1.0f + (float)((w >> (e ^ 1)) & 1u);
        const float* cp = tbl + n * 256 + (h * 16 + (e >> 1)) * 2;
        float cc = cp[0], ss2 = cp[1];
        qrs[r][e] = (e & 1) ? (ss2 * qo + cc * qd) : (cc * qd - ss2 * qo);
        float p = ((w >> e) & 1u) ? kmf[e] : 0.0f;
        #pragma unroll
        for (int m = 1; m < 32; m <<= 1) p += __shfl_xor(p, m);
        float z = 1.0f / (S + p + 1e-6f);
        __syncthreads();
        float o = 0.f;
        #pragma unroll
        for (int dd = 0; dd < 32; dd += 4) {
            float4 q4 = *(const float4*)&qrs[r][dd];
            o = fmaf(q4.x, kvs[dd][e], o);
            o = fmaf(q4.y, kvs[dd + 1][e], o);
            o = fmaf(q4.z, kvs[dd + 2][e], o);
            o = fmaf(q4.w, kvs[dd + 3][e], o);
        }
        o *= z;
        int y = n >> 5, xx = n & 31;
        float l = lbv;
        #pragma unroll
        for (int dy = -1; dy <= 1; ++dy) {
            int yy = y + dy;
            if (yy < 0 || yy > 31) continue;
            #pragma unroll
            for (int dx = -1; dx <= 1; ++dx) {
                int xw = xx + dx;
                if (xw < 0 || xw > 31) continue;
                l = fmaf(w9[(dy + 1) * 3 + (dx + 1)],
                         x[(b * 1024 + yy * 32 + xw) * 256 + c], l);
            }
        }
        out[(b * 1024 + n) * 256 + c] = o + l;
        __syncthreads();
    }
}

// ---------------- qh / kh regeneration ----------------
__global__ __launch_bounds__(256) void qhkh_kernel(
    const unsigned* __restrict__ mq, const unsigned* __restrict__ mk,
    float* __restrict__ out)
{
    int id = blockIdx.x * 256 + threadIdx.x;   // 1048576
    int tensor = id >> 19;
    int r = id & 524287;
    const unsigned* m = tensor ? mk : mq;
    unsigned w = m[r >> 3];
    int d0 = (r & 7) * 4;
    float4 o;
    o.x = 1.0f + (float)((w >> d0) & 1u);
    o.y = 1.0f + (float)((w >> (d0 + 1)) & 1u);
    o.z = 1.0f + (float)((w >> (d0 + 2)) & 1u);
    o.w = 1.0f + (float)((w >> (d0 + 3)) & 1u);
    float* dst = out + (tensor ? OFF_KH : OFF_QH);
    ((float4*)dst)[r] = o;
}

// ---------------- v_img = transpose of x per batch ----------------
__global__ __launch_bounds__(256) void vimg_kernel(
    const float* __restrict__ x, float* __restrict__ v)
{
    __shared__ float s[32][33];
    int t = threadIdx.x;
    int tx = t & 31, ty = t >> 5;
    int bidx = blockIdx.x;
    int b = bidx >> 8;          // 8 batches x 256 tiles
    int tile = bidx & 255;      // 32 p-tiles x 8 c-tiles
    int p0 = (tile >> 3) * 32;
    int c0 = (tile & 7) * 32;
    #pragma unroll
    for (int i = 0; i < 4; ++i) {
        int row = ty * 4 + i;
        s[row][tx] = x[(b * 1024 + p0 + row) * 256 + c0 + tx];
    }
    __syncthreads();
    #pragma unroll
    for (int i = 0; i < 4; ++i) {
        int row = ty * 4 + i;
        v[(b * 256 + c0 + row) * 1024 + p0 + tx] = s[tx][row];
    }
}

extern "C" void kernel_launch(void* const* d_in, const int* in_sizes, int n_in,
                              void* d_out, int out_size, void* d_ws, size_t ws_size,
                              hipStream_t stream)
{
    const float* x     = (const float*)d_in[0];
    const float* Wqk   = (const float*)d_in[1];
    const float* bqk   = (const float*)d_in[2];
    const float* gamma = (const float*)d_in[3];
    const float* beta  = (const float*)d_in[4];
    const float* lw    = (const float*)d_in[5];
    const float* lb    = (const float*)d_in[6];
    float* out = (float*)d_out;
    unsigned* ws = (unsigned*)d_ws;
    unsigned* mq = ws + WS_MQ;
    unsigned* mk = ws + WS_MK;
    float* tbl  = (float*)(ws + WS_TBL);
    float* kvws = (float*)(ws + WS_KV);
    float* kms  = (float*)(ws + WS_KMS);

    hipLaunchKernelGGL(rope_tbl_kernel, dim3(512), dim3(256), 0, stream, tbl);
    hipLaunchKernelGGL(qk_lif_kernel, dim3(256), dim3(512), 0, stream,
                       x, Wqk, bqk, gamma, beta, mq, mk);
    hipLaunchKernelGGL(vimg_kernel, dim3(2048), dim3(256), 0, stream,
                       x, out + OFF_VIMG);
    hipLaunchKernelGGL(qhkh_kernel, dim3(4096), dim3(256), 0, stream, mq, mk, out);
    hipLaunchKernelGGL(atten_kernel, dim3(2048), dim3(256), 0, stream,
                       mq, mk, out + OFF_ATT);
    hipLaunchKernelGGL(kv_kernel, dim3(64), dim3(256), 0, stream,
                       mk, x, tbl, kvws, kms);
    hipLaunchKernelGGL(out_kernel, dim3(512), dim3(256), 0, stream,
                       mq, x, tbl, kvws, kms, lw, lb, out + OFF_OUT);
}

// Round 2
// 186.529 us; speedup vs baseline: 1.8909x; 1.8909x over previous
//
#include <hip/hip_runtime.h>
#include <cstdint>
#include <cstddef>

// Outputs concat (f32): out(8,1024,256) qh(8,8,1024,32) kh(8,8,1024,32)
//                       v_img(8,256,32,32) atten(8,8,1024,1024)
#define OFF_OUT   0
#define OFF_QH    2097152
#define OFF_KH    4194304
#define OFF_VIMG  6291456
#define OFF_ATT   8388608

// ws layout (4-byte units)
#define WS_MQ   0        // 8*8*1024 u32
#define WS_MK   65536
#define WS_TBL  131072   // 1024*128*2 f32 (cos,sin interleaved)
#define WS_KVP  393216   // 64 bh * 4 seg * 32*32 f32 partial kv
#define WS_KMP  655360   // 64 bh * 4 seg * 32 f32 partial k-bit counts

typedef float f32x4 __attribute__((ext_vector_type(4)));

// ---------------- fused GEMM + BN + LIF + bit-pack ----------------
// grid 256 blocks (4 n-rows each), 512 threads (thread = output channel c)
__global__ __launch_bounds__(512) void qk_lif_kernel(
    const float* __restrict__ x, const float* __restrict__ Wqk,
    const float* __restrict__ bqk, const float* __restrict__ gamma,
    const float* __restrict__ beta, unsigned* __restrict__ mq,
    unsigned* __restrict__ mk)
{
    int t = threadIdx.x;          // channel c in [0,512)
    int n0 = blockIdx.x * 4;
    float acc[32];
    #pragma unroll
    for (int i = 0; i < 32; ++i) acc[i] = 0.f;
    const float* xb = x + n0 * 256;       // x[(b*1024+n0+r)*256 + k]
    #pragma unroll 4
    for (int k = 0; k < 256; ++k) {
        float w = Wqk[k * 512 + t];
        #pragma unroll
        for (int b = 0; b < 8; ++b) {
            #pragma unroll
            for (int r = 0; r < 4; ++r)
                acc[b * 4 + r] = fmaf(xb[b * 262144 + r * 256 + k], w, acc[b * 4 + r]);
        }
    }
    float bb = bqk[t];
    #pragma unroll
    for (int r = 0; r < 4; ++r) {
        int n = n0 + r;
        float g = gamma[n], be = beta[n];
        float v = 0.f;
        #pragma unroll
        for (int b = 0; b < 8; ++b) {
            float val = (acc[b * 4 + r] + bb) * g + be;
            v = v + (val - v) * 0.5f;                     // TAU = 2
            bool sp = (v >= 1.0f);
            unsigned long long m = __ballot(sp ? 1 : 0);
            if ((t & 31) == 0) {
                unsigned word = (t & 32) ? (unsigned)(m >> 32) : (unsigned)m;
                unsigned hd = (unsigned)(t >> 5) & 7u;
                unsigned* dst = (t < 256) ? mq : mk;
                dst[b * 8192 + hd * 1024 + n] = word;
            }
            v = sp ? 0.0f : v;
        }
    }
}

// ---------------- misc: vimg transpose (blocks < 2048) + rope table ----------
__global__ __launch_bounds__(256) void misc_kernel(
    const float* __restrict__ x, float* __restrict__ vimg,
    float* __restrict__ tbl)
{
    int t = threadIdx.x;
    if (blockIdx.x >= 2048) {
        int id = (blockIdx.x - 2048) * 256 + t;   // 131072 total
        int j = id & 127, n = id >> 7;
        int i = (j < 64) ? j : j - 64;
        float th = powf(10000.0f, -(float)i * (1.0f / 64.0f));
        float pos = (float)((j < 64) ? (n >> 5) : (n & 31));
        float ang = pos * th;
        tbl[n * 256 + j * 2]     = cosf(ang);
        tbl[n * 256 + j * 2 + 1] = sinf(ang);
        return;
    }
    __shared__ float s[32][33];
    int b = blockIdx.x >> 8;
    int tile = blockIdx.x & 255;       // 32 p-tiles x 8 c-tiles
    int p0 = (tile >> 3) * 32, c0 = (tile & 7) * 32;
    int row = t >> 3, c4 = (t & 7) * 4;
    const float4 vl = *(const float4*)&x[(b * 1024 + p0 + row) * 256 + c0 + c4];
    s[row][c4 + 0] = vl.x; s[row][c4 + 1] = vl.y;
    s[row][c4 + 2] = vl.z; s[row][c4 + 3] = vl.w;
    __syncthreads();
    int cc = t >> 3, p4 = (t & 7) * 4;
    f32x4 o;
    o.x = s[p4 + 0][cc]; o.y = s[p4 + 1][cc];
    o.z = s[p4 + 2][cc]; o.w = s[p4 + 3][cc];
    __builtin_nontemporal_store(o, (f32x4*)&vimg[(b * 256 + c0 + cc) * 1024 + p0 + p4]);
}

// ---------------- atten + qh/kh regen ----------------
// grid 64*32 blocks, 256 threads
__global__ __launch_bounds__(256) void atten_kernel(
    const unsigned* __restrict__ mq, const unsigned* __restrict__ mk,
    float* __restrict__ qh, float* __restrict__ kh, float* __restrict__ att)
{
    int t = threadIdx.x;
    int bh = blockIdx.x >> 5;
    int tile = blockIdx.x & 31;
    // qh/kh for this block's 32 rows
    {
        int row = tile * 32 + (t >> 3);
        int d0 = (t & 7) * 4;
        unsigned wq = mq[bh * 1024 + row], wk = mk[bh * 1024 + row];
        f32x4 a, bb;
        a.x = 1.f + (float)((wq >> (d0 + 0)) & 1u);
        a.y = 1.f + (float)((wq >> (d0 + 1)) & 1u);
        a.z = 1.f + (float)((wq >> (d0 + 2)) & 1u);
        a.w = 1.f + (float)((wq >> (d0 + 3)) & 1u);
        bb.x = 1.f + (float)((wk >> (d0 + 0)) & 1u);
        bb.y = 1.f + (float)((wk >> (d0 + 1)) & 1u);
        bb.z = 1.f + (float)((wk >> (d0 + 2)) & 1u);
        bb.w = 1.f + (float)((wk >> (d0 + 3)) & 1u);
        __builtin_nontemporal_store(a,  (f32x4*)&qh[((bh * 1024 + row) << 5) + d0]);
        __builtin_nontemporal_store(bb, (f32x4*)&kh[((bh * 1024 + row) << 5) + d0]);
    }
    uint4 mm = ((const uint4*)(mk + bh * 1024))[t];
    float4 rr;
    rr.x = (float)__popc(mm.x); rr.y = (float)__popc(mm.y);
    rr.z = (float)__popc(mm.z); rr.w = (float)__popc(mm.w);
    float* base = att + ((size_t)bh * 1024 + (size_t)tile * 32) * 1024;
    for (int row = 0; row < 32; ++row) {
        unsigned mqw = mq[bh * 1024 + tile * 32 + row];
        float rq = 32.0f + (float)__popc(mqw);
        f32x4 o;
        o.x = rq + rr.x + (float)__popc(mqw & mm.x);
        o.y = rq + rr.y + (float)__popc(mqw & mm.y);
        o.z = rq + rr.z + (float)__popc(mqw & mm.z);
        o.w = rq + rr.w + (float)__popc(mqw & mm.w);
        __builtin_nontemporal_store(o, (f32x4*)(base + (size_t)row * 1024) + t);
    }
}

// ---------------- partial kv + k-bit counts per (b,h,seg of 256 n) ----------
__global__ __launch_bounds__(256) void kv_kernel(
    const unsigned* __restrict__ mk, const float* __restrict__ x,
    const float* __restrict__ tbl, float* __restrict__ kvp,
    float* __restrict__ kmp)
{
    int t = threadIdx.x;
    int bh = blockIdx.x >> 2, seg = blockIdx.x & 3;
    int b = bh >> 3, h = bh & 7;
    int n0 = seg * 256;
    __shared__ float part[8][32];
    __shared__ float kr[64][36];
    __shared__ float vhs[64][33];
    int d = t & 31, ch = t >> 5;
    int sc = 0;
    for (int i = 0; i < 32; ++i)
        sc += (mk[bh * 1024 + n0 + ch * 32 + i] >> d) & 1u;
    part[ch][d] = (float)sc;
    __syncthreads();
    if (t < 32) {
        float cs = 0.f;
        #pragma unroll
        for (int j = 0; j < 8; ++j) cs += part[j][t];
        kmp[bh * 128 + seg * 32 + t] = cs;
    }
    float a0 = 0, a1 = 0, a2 = 0, a3 = 0;
    int e = t & 31, db = (t >> 5) * 4;
    for (int c0 = n0; c0 < n0 + 256; c0 += 64) {
        __syncthreads();
        #pragma unroll
        for (int i = 0; i < 8; ++i) {
            int f = t + i * 256;
            int nn = f >> 5, dd = f & 31;
            int n = c0 + nn;
            unsigned w = mk[bh * 1024 + n];
            float kd = 1.0f + (float)((w >> dd) & 1u);
            float ko = 1.0f + (float)((w >> (dd ^ 1)) & 1u);
            const float* cp = tbl + n * 256 + h * 32 + (dd & ~1);
            float cc2 = cp[0], ss2 = cp[1];
            kr[nn][dd] = (dd & 1) ? (ss2 * ko + cc2 * kd) : (cc2 * kd - ss2 * ko);
            vhs[nn][dd] = x[(b * 1024 + n) * 256 + h * 32 + dd];
        }
        __syncthreads();
        #pragma unroll 8
        for (int nn = 0; nn < 64; ++nn) {
            float ve = vhs[nn][e];
            float4 kk = *(const float4*)&kr[nn][db];
            a0 = fmaf(kk.x, ve, a0); a1 = fmaf(kk.y, ve, a1);
            a2 = fmaf(kk.z, ve, a2); a3 = fmaf(kk.w, ve, a3);
        }
    }
    float* dst = kvp + bh * 4096 + seg * 1024;
    dst[(db + 0) * 32 + e] = a0;
    dst[(db + 1) * 32 + e] = a1;
    dst[(db + 2) * 32 + e] = a2;
    dst[(db + 3) * 32 + e] = a3;
}

// ---------------- out = q_rope@kv * z + lepe ----------------
// grid 64 bh * 8 (4 p-segments x 2 halves), 256 threads = (p_l 0..7, e 0..31)
// head h<4: RoPE phase depends only on y -> thread fixes y=p, iterates x.
// head h>=4: phase depends only on x -> thread fixes x=p, iterates y.
__global__ __launch_bounds__(256) void out_kernel(
    const unsigned* __restrict__ mq, const float* __restrict__ x,
    const float* __restrict__ tbl, const float* __restrict__ kvp,
    const float* __restrict__ kmp, const float* __restrict__ lw,
    const float* __restrict__ lb, float* __restrict__ out)
{
    int t = threadIdx.x;
    int bi = blockIdx.x;
    int bh = bi >> 3, sub = bi & 7;
    int pseg = sub >> 1, half = sub & 1;
    int b = bh >> 3, h = bh & 7;
    bool hy = (h < 4);
    int e = t & 31, p_l = t >> 5;
    int p = pseg * 8 + p_l;
    int q0 = half * 16;

    __shared__ float kvs[32][32];
    __shared__ float kmf[32];
    __shared__ float zs[128];
    const float inv = 1.0f / 1024.0f;
    #pragma unroll
    for (int i = 0; i < 4; ++i) {
        int f = t + i * 256;
        const float* kp = kvp + bh * 4096 + f;
        kvs[f >> 5][f & 31] = (kp[0] + kp[1024] + kp[2048] + kp[3072]) * inv;
    }
    if (t < 32) {
        const float* mp = kmp + bh * 128 + t;
        kmf[t] = 1.0f + (mp[0] + mp[32] + mp[64] + mp[96]) * inv;
    }
    __syncthreads();
    float S = 0.f;
    #pragma unroll
    for (int dd = 0; dd < 32; ++dd) S += kmf[dd];
    if (t < 128) {
        int pl2 = t >> 4, iq = t & 15;
        int pp = pseg * 8 + pl2, qq = q0 + iq;
        int n = hy ? (pp * 32 + qq) : (qq * 32 + pp);
        unsigned w = mq[bh * 1024 + n];
        float acc = S;
        #pragma unroll
        for (int dd = 0; dd < 32; ++dd)
            acc += (float)((w >> dd) & 1u) * kmf[dd];
        zs[t] = 1.0f / (acc + 1e-6f);
    }
    // per-thread loop invariants: cos/sin for pos p, kv column e -> E/O/B
    int n_ref = hy ? (p * 32) : p;
    const float* cp = tbl + n_ref * 256 + h * 32;
    float E[16], O[16], B = 0.f;
    #pragma unroll
    for (int j = 0; j < 16; ++j) {
        float c2 = cp[2 * j], s2 = cp[2 * j + 1];
        float K0 = kvs[2 * j][e], K1 = kvs[2 * j + 1][e];
        E[j] = c2 * K0 + s2 * K1;
        O[j] = c2 * K1 - s2 * K0;
        B += E[j] + O[j];
    }
    __syncthreads();
    int c = h * 32 + e;
    float w9[9];
    #pragma unroll
    for (int j = 0; j < 9; ++j) w9[j] = lw[c * 9 + j];
    float lbv = lb[c];
    const float* xb = x + (size_t)b * 262144 + c;
    auto ld = [&](int yy, int xx) -> float {
        if ((unsigned)yy > 31u || (unsigned)xx > 31u) return 0.f;
        return xb[(yy * 32 + xx) * 256];
    };
    if (hy) {
        int y = p;
        float Wm0 = ld(y - 1, q0 - 1), Wm1 = ld(y, q0 - 1), Wm2 = ld(y + 1, q0 - 1);
        float Wc0 = ld(y - 1, q0),     Wc1 = ld(y, q0),     Wc2 = ld(y + 1, q0);
        #pragma unroll 4
        for (int i = 0; i < 16; ++i) {
            int m = q0 + i;
            float Wp0 = ld(y - 1, m + 1), Wp1 = ld(y, m + 1), Wp2 = ld(y + 1, m + 1);
            int n = y * 32 + m;
            unsigned w = mq[bh * 1024 + n];
            float o = B;
            #pragma unroll
            for (int j = 0; j < 16; ++j) {
                o += (float)((w >> (2 * j)) & 1u) * E[j];
                o += (float)((w >> (2 * j + 1)) & 1u) * O[j];
            }
            o *= zs[p_l * 16 + i];
            float l = lbv;
            l = fmaf(w9[0], Wm0, l); l = fmaf(w9[1], Wc0, l); l = fmaf(w9[2], Wp0, l);
            l = fmaf(w9[3], Wm1, l); l = fmaf(w9[4], Wc1, l); l = fmaf(w9[5], Wp1, l);
            l = fmaf(w9[6], Wm2, l); l = fmaf(w9[7], Wc2, l); l = fmaf(w9[8], Wp2, l);
            __builtin_nontemporal_store(o + l, &out[((b * 1024 + n) << 8) + c]);
            Wm0 = Wc0; Wm1 = Wc1; Wm2 = Wc2;
            Wc0 = Wp0; Wc1 = Wp1; Wc2 = Wp2;
        }
    } else {
        int xx0 = p;
        float Wm0 = ld(q0 - 1, xx0 - 1), Wm1 = ld(q0 - 1, xx0), Wm2 = ld(q0 - 1, xx0 + 1);
        float Wc0 = ld(q0, xx0 - 1),     Wc1 = ld(q0, xx0),     Wc2 = ld(q0, xx0 + 1);
        #pragma unroll 4
        for (int i = 0; i < 16; ++i) {
            int m = q0 + i;
            float Wp0 = ld(m + 1, xx0 - 1), Wp1 = ld(m + 1, xx0), Wp2 = ld(m + 1, xx0 + 1);
            int n = m * 32 + xx0;
            unsigned w = mq[bh * 1024 + n];
            float o = B;
            #pragma unroll
            for (int j = 0; j < 16; ++j) {
                o += (float)((w >> (2 * j)) & 1u) * E[j];
                o += (float)((w >> (2 * j + 1)) & 1u) * O[j];
            }
            o *= zs[p_l * 16 + i];
            float l = lbv;
            l = fmaf(w9[0], Wm0, l); l = fmaf(w9[1], Wm1, l); l = fmaf(w9[2], Wm2, l);
            l = fmaf(w9[3], Wc0, l); l = fmaf(w9[4], Wc1, l); l = fmaf(w9[5], Wc2, l);
            l = fmaf(w9[6], Wp0, l); l = fmaf(w9[7], Wp1, l); l = fmaf(w9[8], Wp2, l);
            __builtin_nontemporal_store(o + l, &out[((b * 1024 + n) << 8) + c]);
            Wm0 = Wc0; Wm1 = Wc1; Wm2 = Wc2;
            Wc0 = Wp0; Wc1 = Wp1; Wc2 = Wp2;
        }
    }
}

extern "C" void kernel_launch(void* const* d_in, const int* in_sizes, int n_in,
                              void* d_out, int out_size, void* d_ws, size_t ws_size,
                              hipStream_t stream)
{
    const float* x     = (const float*)d_in[0];
    const float* Wqk   = (const float*)d_in[1];
    const float* bqk   = (const float*)d_in[2];
    const float* gamma = (const float*)d_in[3];
    const float* beta  = (const float*)d_in[4];
    const float* lw    = (const float*)d_in[5];
    const float* lb    = (const float*)d_in[6];
    float* out = (float*)d_out;
    unsigned* ws = (unsigned*)d_ws;
    unsigned* mq = ws + WS_MQ;
    unsigned* mk = ws + WS_MK;
    float* tbl  = (float*)(ws + WS_TBL);
    float* kvp  = (float*)(ws + WS_KVP);
    float* kmp  = (float*)(ws + WS_KMP);

    hipLaunchKernelGGL(qk_lif_kernel, dim3(256), dim3(512), 0, stream,
                       x, Wqk, bqk, gamma, beta, mq, mk);
    hipLaunchKernelGGL(misc_kernel, dim3(2560), dim3(256), 0, stream,
                       x, out + OFF_VIMG, tbl);
    hipLaunchKernelGGL(kv_kernel, dim3(256), dim3(256), 0, stream,
                       mk, x, tbl, kvp, kmp);
    hipLaunchKernelGGL(atten_kernel, dim3(2048), dim3(256), 0, stream,
                       mq, mk, out + OFF_QH, out + OFF_KH, out + OFF_ATT);
    hipLaunchKernelGGL(out_kernel, dim3(512), dim3(256), 0, stream,
                       mq, x, tbl, kvp, kmp, lw, lb, out + OFF_OUT);
}

// Round 3
// 119.797 us; speedup vs baseline: 2.9442x; 1.5570x over previous
//
#include <hip/hip_runtime.h>
#include <cstdint>
#include <cstddef>

// Outputs concat (f32): out(8,1024,256) qh(8,8,1024,32) kh(8,8,1024,32)
//                       v_img(8,256,32,32) atten(8,8,1024,1024)
#define OFF_OUT   0
#define OFF_QH    2097152
#define OFF_KH    4194304
#define OFF_VIMG  6291456
#define OFF_ATT   8388608

// ws layout (4-byte units)
#define WS_MQ   0        // 8*8*1024 u32
#define WS_MK   65536
#define WS_TBL  131072   // 1024*128*2 f32 (cos,sin interleaved)
#define WS_KVP  393216   // 64 bh * 4 seg * 32*32 f32 partial kv
#define WS_KMP  655360   // 64 bh * 4 seg * 32 f32 partial k-bit counts

typedef float f32x4 __attribute__((ext_vector_type(4)));

// ---------------- fused tiled GEMM + BN + LIF + bit-pack ----------------
// grid 512 blocks (128 n-tiles x 4 c-tiles), 256 threads.
// Block tile: 8 n x 8 b (rows m = n_l*8 + b) x 128 c.  Thread: 8 b x 4 c.
// K=256 in 8 panels of 32, LDS-staged, register double-buffered.
__global__ __launch_bounds__(256) void qk_lif_kernel(
    const float* __restrict__ x, const float* __restrict__ Wqk,
    const float* __restrict__ bqk, const float* __restrict__ gamma,
    const float* __restrict__ beta, unsigned* __restrict__ mq,
    unsigned* __restrict__ mk)
{
    __shared__ float xs[32][68];        // [k][m], pad 68 (16B-aligned rows)
    __shared__ float ws[32][132];       // [k][c_local], pad 132
    __shared__ unsigned nib[8][4][8][8];// [n_l][h'][c8][b]
    int t = threadIdx.x;
    int blk_n = blockIdx.x >> 2, blk_c = blockIdx.x & 3;
    int n0 = blk_n * 8, c0 = blk_c * 128;
    int c_t = t & 31, n_l = t >> 5;

    float acc[8][4];
    #pragma unroll
    for (int b = 0; b < 8; ++b)
        #pragma unroll
        for (int j = 0; j < 4; ++j) acc[b][j] = 0.f;

    // x staging tasks: u in [0,512): m = u>>3 (b = m&7, nl = m>>3), kq = u&7
    int um = t >> 3, ukq = t & 7;
    const float* gx1 = x + ((size_t)(um & 7) * 1024 + n0 + (um >> 3)) * 256 + ukq * 4;
    const float* gx2 = x + ((size_t)(um & 7) * 1024 + n0 + (um >> 3) + 4) * 256 + ukq * 4;
    float* lx1 = &xs[ukq * 4][um];
    float* lx2 = &xs[ukq * 4][um + 32];
    // W staging tasks: 4 per thread: k = (t>>5) + 8*i, cq = t&31
    int uwk = t >> 5, uwc = t & 31;
    const float* gw = Wqk + (size_t)uwk * 512 + c0 + uwc * 4;
    float* lw0 = &ws[uwk][uwc * 4];

    f32x4 px0, px1, pw0, pw1, pw2, pw3;
    px0 = *(const f32x4*)(gx1);
    px1 = *(const f32x4*)(gx2);
    pw0 = *(const f32x4*)(gw);
    pw1 = *(const f32x4*)(gw + 8 * 512);
    pw2 = *(const f32x4*)(gw + 16 * 512);
    pw3 = *(const f32x4*)(gw + 24 * 512);

    for (int p = 0; p < 8; ++p) {
        // write staged panel to LDS
        #pragma unroll
        for (int j = 0; j < 4; ++j) { lx1[j * 68] = px0[j]; lx2[j * 68] = px1[j]; }
        *(f32x4*)(lw0)            = pw0;
        *(f32x4*)(lw0 + 8 * 132)  = pw1;
        *(f32x4*)(lw0 + 16 * 132) = pw2;
        *(f32x4*)(lw0 + 24 * 132) = pw3;
        __syncthreads();
        // prefetch next panel
        if (p < 7) {
            int ko = (p + 1) * 32;
            px0 = *(const f32x4*)(gx1 + ko);
            px1 = *(const f32x4*)(gx2 + ko);
            pw0 = *(const f32x4*)(gw + (ko + 0) * 512);
            pw1 = *(const f32x4*)(gw + (ko + 8) * 512);
            pw2 = *(const f32x4*)(gw + (ko + 16) * 512);
            pw3 = *(const f32x4*)(gw + (ko + 24) * 512);
        }
        // compute panel
        #pragma unroll 8
        for (int kk = 0; kk < 32; ++kk) {
            f32x4 xa = *(const f32x4*)&xs[kk][n_l * 8];
            f32x4 xb2 = *(const f32x4*)&xs[kk][n_l * 8 + 4];
            f32x4 w4 = *(const f32x4*)&ws[kk][c_t * 4];
            #pragma unroll
            for (int b = 0; b < 4; ++b)
                #pragma unroll
                for (int j = 0; j < 4; ++j)
                    acc[b][j] = fmaf(xa[b], w4[j], acc[b][j]);
            #pragma unroll
            for (int b = 0; b < 4; ++b)
                #pragma unroll
                for (int j = 0; j < 4; ++j)
                    acc[b + 4][j] = fmaf(xb2[b], w4[j], acc[b + 4][j]);
        }
        __syncthreads();
    }

    // LIF scan over b (thread-local) + nibble pack
    float g = gamma[n0 + n_l], be = beta[n0 + n_l];
    f32x4 bq = *(const f32x4*)&bqk[c0 + c_t * 4];
    float v0 = 0.f, v1 = 0.f, v2 = 0.f, v3 = 0.f;
    #pragma unroll
    for (int b = 0; b < 8; ++b) {
        float a0 = (acc[b][0] + bq[0]) * g + be;
        float a1 = (acc[b][1] + bq[1]) * g + be;
        float a2 = (acc[b][2] + bq[2]) * g + be;
        float a3 = (acc[b][3] + bq[3]) * g + be;
        v0 = v0 + (a0 - v0) * 0.5f; v1 = v1 + (a1 - v1) * 0.5f;
        v2 = v2 + (a2 - v2) * 0.5f; v3 = v3 + (a3 - v3) * 0.5f;
        unsigned s0 = (v0 >= 1.f), s1 = (v1 >= 1.f), s2 = (v2 >= 1.f), s3 = (v3 >= 1.f);
        v0 = s0 ? 0.f : v0; v1 = s1 ? 0.f : v1;
        v2 = s2 ? 0.f : v2; v3 = s3 ? 0.f : v3;
        nib[n_l][c_t >> 3][c_t & 7][b] = s0 | (s1 << 1) | (s2 << 2) | (s3 << 3);
    }
    __syncthreads();
    // word assembly: t -> (b, h', n_l')
    {
        int b = t & 7, hp = (t >> 3) & 3, nl = t >> 5;
        unsigned wd = 0;
        #pragma unroll
        for (int c8 = 0; c8 < 8; ++c8)
            wd |= nib[nl][hp][c8][b] << (4 * c8);
        unsigned h = (unsigned)((blk_c & 1) * 4 + hp);
        unsigned* dst = (blk_c < 2) ? mq : mk;
        dst[b * 8192 + h * 1024 + n0 + nl] = wd;
    }
}

// ---------------- misc: vimg transpose (blocks < 2048) + rope table ----------
__global__ __launch_bounds__(256) void misc_kernel(
    const float* __restrict__ x, float* __restrict__ vimg,
    float* __restrict__ tbl)
{
    int t = threadIdx.x;
    if (blockIdx.x >= 2048) {
        int id = (blockIdx.x - 2048) * 256 + t;   // 131072 total
        int j = id & 127, n = id >> 7;
        int i = (j < 64) ? j : j - 64;
        float th = powf(10000.0f, -(float)i * (1.0f / 64.0f));
        float pos = (float)((j < 64) ? (n >> 5) : (n & 31));
        float ang = pos * th;
        tbl[n * 256 + j * 2]     = cosf(ang);
        tbl[n * 256 + j * 2 + 1] = sinf(ang);
        return;
    }
    __shared__ float s[32][33];
    int b = blockIdx.x >> 8;
    int tile = blockIdx.x & 255;       // 32 p-tiles x 8 c-tiles
    int p0 = (tile >> 3) * 32, c0 = (tile & 7) * 32;
    int row = t >> 3, c4 = (t & 7) * 4;
    const float4 vl = *(const float4*)&x[(b * 1024 + p0 + row) * 256 + c0 + c4];
    s[row][c4 + 0] = vl.x; s[row][c4 + 1] = vl.y;
    s[row][c4 + 2] = vl.z; s[row][c4 + 3] = vl.w;
    __syncthreads();
    int cc = t >> 3, p4 = (t & 7) * 4;
    f32x4 o;
    o.x = s[p4 + 0][cc]; o.y = s[p4 + 1][cc];
    o.z = s[p4 + 2][cc]; o.w = s[p4 + 3][cc];
    __builtin_nontemporal_store(o, (f32x4*)&vimg[(b * 256 + c0 + cc) * 1024 + p0 + p4]);
}

// ---------------- atten + qh/kh regen ----------------
__global__ __launch_bounds__(256) void atten_kernel(
    const unsigned* __restrict__ mq, const unsigned* __restrict__ mk,
    float* __restrict__ qh, float* __restrict__ kh, float* __restrict__ att)
{
    int t = threadIdx.x;
    int bh = blockIdx.x >> 5;
    int tile = blockIdx.x & 31;
    {
        int row = tile * 32 + (t >> 3);
        int d0 = (t & 7) * 4;
        unsigned wq = mq[bh * 1024 + row], wk = mk[bh * 1024 + row];
        f32x4 a, bb;
        a.x = 1.f + (float)((wq >> (d0 + 0)) & 1u);
        a.y = 1.f + (float)((wq >> (d0 + 1)) & 1u);
        a.z = 1.f + (float)((wq >> (d0 + 2)) & 1u);
        a.w = 1.f + (float)((wq >> (d0 + 3)) & 1u);
        bb.x = 1.f + (float)((wk >> (d0 + 0)) & 1u);
        bb.y = 1.f + (float)((wk >> (d0 + 1)) & 1u);
        bb.z = 1.f + (float)((wk >> (d0 + 2)) & 1u);
        bb.w = 1.f + (float)((wk >> (d0 + 3)) & 1u);
        __builtin_nontemporal_store(a,  (f32x4*)&qh[((bh * 1024 + row) << 5) + d0]);
        __builtin_nontemporal_store(bb, (f32x4*)&kh[((bh * 1024 + row) << 5) + d0]);
    }
    uint4 mm = ((const uint4*)(mk + bh * 1024))[t];
    float4 rr;
    rr.x = (float)__popc(mm.x); rr.y = (float)__popc(mm.y);
    rr.z = (float)__popc(mm.z); rr.w = (float)__popc(mm.w);
    float* base = att + ((size_t)bh * 1024 + (size_t)tile * 32) * 1024;
    for (int row = 0; row < 32; ++row) {
        unsigned mqw = mq[bh * 1024 + tile * 32 + row];
        float rq = 32.0f + (float)__popc(mqw);
        f32x4 o;
        o.x = rq + rr.x + (float)__popc(mqw & mm.x);
        o.y = rq + rr.y + (float)__popc(mqw & mm.y);
        o.z = rq + rr.z + (float)__popc(mqw & mm.z);
        o.w = rq + rr.w + (float)__popc(mqw & mm.w);
        __builtin_nontemporal_store(o, (f32x4*)(base + (size_t)row * 1024) + t);
    }
}

// ---------------- partial kv + k-bit counts per (b,h,seg of 256 n) ----------
__global__ __launch_bounds__(256) void kv_kernel(
    const unsigned* __restrict__ mk, const float* __restrict__ x,
    const float* __restrict__ tbl, float* __restrict__ kvp,
    float* __restrict__ kmp)
{
    int t = threadIdx.x;
    int bh = blockIdx.x >> 2, seg = blockIdx.x & 3;
    int b = bh >> 3, h = bh & 7;
    int n0 = seg * 256;
    __shared__ float part[8][32];
    __shared__ float kr[64][36];
    __shared__ float vhs[64][33];
    int d = t & 31, ch = t >> 5;
    int sc = 0;
    for (int i = 0; i < 32; ++i)
        sc += (mk[bh * 1024 + n0 + ch * 32 + i] >> d) & 1u;
    part[ch][d] = (float)sc;
    __syncthreads();
    if (t < 32) {
        float cs = 0.f;
        #pragma unroll
        for (int j = 0; j < 8; ++j) cs += part[j][t];
        kmp[bh * 128 + seg * 32 + t] = cs;
    }
    float a0 = 0, a1 = 0, a2 = 0, a3 = 0;
    int e = t & 31, db = (t >> 5) * 4;
    for (int c0 = n0; c0 < n0 + 256; c0 += 64) {
        __syncthreads();
        #pragma unroll
        for (int i = 0; i < 8; ++i) {
            int f = t + i * 256;
            int nn = f >> 5, dd = f & 31;
            int n = c0 + nn;
            unsigned w = mk[bh * 1024 + n];
            float kd = 1.0f + (float)((w >> dd) & 1u);
            float ko = 1.0f + (float)((w >> (dd ^ 1)) & 1u);
            const float* cp = tbl + n * 256 + h * 32 + (dd & ~1);
            float cc2 = cp[0], ss2 = cp[1];
            kr[nn][dd] = (dd & 1) ? (ss2 * ko + cc2 * kd) : (cc2 * kd - ss2 * ko);
            vhs[nn][dd] = x[(b * 1024 + n) * 256 + h * 32 + dd];
        }
        __syncthreads();
        #pragma unroll 8
        for (int nn = 0; nn < 64; ++nn) {
            float ve = vhs[nn][e];
            float4 kk = *(const float4*)&kr[nn][db];
            a0 = fmaf(kk.x, ve, a0); a1 = fmaf(kk.y, ve, a1);
            a2 = fmaf(kk.z, ve, a2); a3 = fmaf(kk.w, ve, a3);
        }
    }
    float* dst = kvp + bh * 4096 + seg * 1024;
    dst[(db + 0) * 32 + e] = a0;
    dst[(db + 1) * 32 + e] = a1;
    dst[(db + 2) * 32 + e] = a2;
    dst[(db + 3) * 32 + e] = a3;
}

// ---------------- out = q_rope@kv * z + lepe ----------------
__global__ __launch_bounds__(256) void out_kernel(
    const unsigned* __restrict__ mq, const float* __restrict__ x,
    const float* __restrict__ tbl, const float* __restrict__ kvp,
    const float* __restrict__ kmp, const float* __restrict__ lw,
    const float* __restrict__ lb, float* __restrict__ out)
{
    int t = threadIdx.x;
    int bi = blockIdx.x;
    int bh = bi >> 3, sub = bi & 7;
    int pseg = sub >> 1, half = sub & 1;
    int b = bh >> 3, h = bh & 7;
    bool hy = (h < 4);
    int e = t & 31, p_l = t >> 5;
    int p = pseg * 8 + p_l;
    int q0 = half * 16;

    __shared__ float kvs[32][32];
    __shared__ float kmf[32];
    __shared__ float zs[128];
    const float inv = 1.0f / 1024.0f;
    #pragma unroll
    for (int i = 0; i < 4; ++i) {
        int f = t + i * 256;
        const float* kp = kvp + bh * 4096 + f;
        kvs[f >> 5][f & 31] = (kp[0] + kp[1024] + kp[2048] + kp[3072]) * inv;
    }
    if (t < 32) {
        const float* mp = kmp + bh * 128 + t;
        kmf[t] = 1.0f + (mp[0] + mp[32] + mp[64] + mp[96]) * inv;
    }
    __syncthreads();
    float S = 0.f;
    #pragma unroll
    for (int dd = 0; dd < 32; ++dd) S += kmf[dd];
    if (t < 128) {
        int pl2 = t >> 4, iq = t & 15;
        int pp = pseg * 8 + pl2, qq = q0 + iq;
        int n = hy ? (pp * 32 + qq) : (qq * 32 + pp);
        unsigned w = mq[bh * 1024 + n];
        float acc = S;
        #pragma unroll
        for (int dd = 0; dd < 32; ++dd)
            acc += (float)((w >> dd) & 1u) * kmf[dd];
        zs[t] = 1.0f / (acc + 1e-6f);
    }
    int n_ref = hy ? (p * 32) : p;
    const float* cp = tbl + n_ref * 256 + h * 32;
    float E[16], O[16], B = 0.f;
    #pragma unroll
    for (int j = 0; j < 16; ++j) {
        float c2 = cp[2 * j], s2 = cp[2 * j + 1];
        float K0 = kvs[2 * j][e], K1 = kvs[2 * j + 1][e];
        E[j] = c2 * K0 + s2 * K1;
        O[j] = c2 * K1 - s2 * K0;
        B += E[j] + O[j];
    }
    __syncthreads();
    int c = h * 32 + e;
    float w9[9];
    #pragma unroll
    for (int j = 0; j < 9; ++j) w9[j] = lw[c * 9 + j];
    float lbv = lb[c];
    const float* xb = x + (size_t)b * 262144 + c;
    auto ld = [&](int yy, int xx) -> float {
        if ((unsigned)yy > 31u || (unsigned)xx > 31u) return 0.f;
        return xb[(yy * 32 + xx) * 256];
    };
    if (hy) {
        int y = p;
        float Wm0 = ld(y - 1, q0 - 1), Wm1 = ld(y, q0 - 1), Wm2 = ld(y + 1, q0 - 1);
        float Wc0 = ld(y - 1, q0),     Wc1 = ld(y, q0),     Wc2 = ld(y + 1, q0);
        #pragma unroll 4
        for (int i = 0; i < 16; ++i) {
            int m = q0 + i;
            float Wp0 = ld(y - 1, m + 1), Wp1 = ld(y, m + 1), Wp2 = ld(y + 1, m + 1);
            int n = y * 32 + m;
            unsigned w = mq[bh * 1024 + n];
            float o = B;
            #pragma unroll
            for (int j = 0; j < 16; ++j) {
                o += (float)((w >> (2 * j)) & 1u) * E[j];
                o += (float)((w >> (2 * j + 1)) & 1u) * O[j];
            }
            o *= zs[p_l * 16 + i];
            float l = lbv;
            l = fmaf(w9[0], Wm0, l); l = fmaf(w9[1], Wc0, l); l = fmaf(w9[2], Wp0, l);
            l = fmaf(w9[3], Wm1, l); l = fmaf(w9[4], Wc1, l); l = fmaf(w9[5], Wp1, l);
            l = fmaf(w9[6], Wm2, l); l = fmaf(w9[7], Wc2, l); l = fmaf(w9[8], Wp2, l);
            __builtin_nontemporal_store(o + l, &out[((b * 1024 + n) << 8) + c]);
            Wm0 = Wc0; Wm1 = Wc1; Wm2 = Wc2;
            Wc0 = Wp0; Wc1 = Wp1; Wc2 = Wp2;
        }
    } else {
        int xx0 = p;
        float Wm0 = ld(q0 - 1, xx0 - 1), Wm1 = ld(q0 - 1, xx0), Wm2 = ld(q0 - 1, xx0 + 1);
        float Wc0 = ld(q0, xx0 - 1),     Wc1 = ld(q0, xx0),     Wc2 = ld(q0, xx0 + 1);
        #pragma unroll 4
        for (int i = 0; i < 16; ++i) {
            int m = q0 + i;
            float Wp0 = ld(m + 1, xx0 - 1), Wp1 = ld(m + 1, xx0), Wp2 = ld(m + 1, xx0 + 1);
            int n = m * 32 + xx0;
            unsigned w = mq[bh * 1024 + n];
            float o = B;
            #pragma unroll
            for (int j = 0; j < 16; ++j) {
                o += (float)((w >> (2 * j)) & 1u) * E[j];
                o += (float)((w >> (2 * j + 1)) & 1u) * O[j];
            }
            o *= zs[p_l * 16 + i];
            float l = lbv;
            l = fmaf(w9[0], Wm0, l); l = fmaf(w9[1], Wm1, l); l = fmaf(w9[2], Wm2, l);
            l = fmaf(w9[3], Wc0, l); l = fmaf(w9[4], Wc1, l); l = fmaf(w9[5], Wc2, l);
            l = fmaf(w9[6], Wp0, l); l = fmaf(w9[7], Wp1, l); l = fmaf(w9[8], Wp2, l);
            __builtin_nontemporal_store(o + l, &out[((b * 1024 + n) << 8) + c]);
            Wm0 = Wc0; Wm1 = Wc1; Wm2 = Wc2;
            Wc0 = Wp0; Wc1 = Wp1; Wc2 = Wp2;
        }
    }
}

extern "C" void kernel_launch(void* const* d_in, const int* in_sizes, int n_in,
                              void* d_out, int out_size, void* d_ws, size_t ws_size,
                              hipStream_t stream)
{
    const float* x     = (const float*)d_in[0];
    const float* Wqk   = (const float*)d_in[1];
    const float* bqk   = (const float*)d_in[2];
    const float* gamma = (const float*)d_in[3];
    const float* beta  = (const float*)d_in[4];
    const float* lw    = (const float*)d_in[5];
    const float* lb    = (const float*)d_in[6];
    float* out = (float*)d_out;
    unsigned* ws = (unsigned*)d_ws;
    unsigned* mq = ws + WS_MQ;
    unsigned* mk = ws + WS_MK;
    float* tbl  = (float*)(ws + WS_TBL);
    float* kvp  = (float*)(ws + WS_KVP);
    float* kmp  = (float*)(ws + WS_KMP);

    hipLaunchKernelGGL(qk_lif_kernel, dim3(512), dim3(256), 0, stream,
                       x, Wqk, bqk, gamma, beta, mq, mk);
    hipLaunchKernelGGL(misc_kernel, dim3(2560), dim3(256), 0, stream,
                       x, out + OFF_VIMG, tbl);
    hipLaunchKernelGGL(kv_kernel, dim3(256), dim3(256), 0, stream,
                       mk, x, tbl, kvp, kmp);
    hipLaunchKernelGGL(atten_kernel, dim3(2048), dim3(256), 0, stream,
                       mq, mk, out + OFF_QH, out + OFF_KH, out + OFF_ATT);
    hipLaunchKernelGGL(out_kernel, dim3(512), dim3(256), 0, stream,
                       mq, x, tbl, kvp, kmp, lw, lb, out + OFF_OUT);
}

// Round 4
// 107.639 us; speedup vs baseline: 3.2768x; 1.1130x over previous
//
#include <hip/hip_runtime.h>
#include <cstdint>
#include <cstddef>

// Outputs concat (f32): out(8,1024,256) qh(8,8,1024,32) kh(8,8,1024,32)
//                       v_img(8,256,32,32) atten(8,8,1024,1024)
#define OFF_OUT   0
#define OFF_QH    2097152
#define OFF_KH    4194304
#define OFF_VIMG  6291456
#define OFF_ATT   8388608

// ws layout (4-byte units)
#define WS_MQ   0        // 8*8*1024 u32
#define WS_MK   65536
#define WS_TBL  131072   // 1024*128*2 f32 (cos,sin interleaved)
#define WS_KVP  393216   // 64 bh * 4 seg * 32*32 f32 partial kv
#define WS_KMP  655360   // 64 bh * 4 seg * 32 f32 partial k-bit counts

typedef float f32x4 __attribute__((ext_vector_type(4)));

// =====================================================================
// Phase 1 (512 thr):
//  blocks [0,512)    : fused GEMM+BN+LIF+pack, k-split across 2 wave-groups
//  blocks [512,1536) : vimg transpose, 2 tiles/block
//  blocks [1536,1792): rope table
// =====================================================================
__global__ __launch_bounds__(512) void phase1_kernel(
    const float* __restrict__ x, const float* __restrict__ Wqk,
    const float* __restrict__ bqk, const float* __restrict__ gamma,
    const float* __restrict__ beta, unsigned* __restrict__ mq,
    unsigned* __restrict__ mk, float* __restrict__ vimg,
    float* __restrict__ tbl)
{
    __shared__ float smem[12800];          // 51.2 KB shared pool
    __shared__ unsigned nib[8][4][8][8];   // [n_l][h'][c8][b]
    int t = threadIdx.x;
    int blk = blockIdx.x;

    if (blk >= 1536) {                     // ---- rope table ----
        int id = (blk - 1536) * 512 + t;   // 131072 total
        int j = id & 127, n = id >> 7;
        int i = (j < 64) ? j : j - 64;
        float th = powf(10000.0f, -(float)i * (1.0f / 64.0f));
        float pos = (float)((j < 64) ? (n >> 5) : (n & 31));
        float ang = pos * th;
        tbl[n * 256 + j * 2]     = cosf(ang);
        tbl[n * 256 + j * 2 + 1] = sinf(ang);
        return;
    }
    if (blk >= 512) {                      // ---- vimg transpose ----
        int tile = (blk - 512) * 2 + (t >> 8);
        int st = t & 255;
        float* s = smem + (t >> 8) * 1056; // [32][33]
        int b = tile >> 8, ti = tile & 255;
        int p0 = (ti >> 3) * 32, c0 = (ti & 7) * 32;
        int row = st >> 3, c4 = (st & 7) * 4;
        const float4 vl = *(const float4*)&x[(b * 1024 + p0 + row) * 256 + c0 + c4];
        s[row * 33 + c4 + 0] = vl.x; s[row * 33 + c4 + 1] = vl.y;
        s[row * 33 + c4 + 2] = vl.z; s[row * 33 + c4 + 3] = vl.w;
        __syncthreads();
        int cc = st >> 3, p4 = (st & 7) * 4;
        f32x4 o;
        o.x = s[(p4 + 0) * 33 + cc]; o.y = s[(p4 + 1) * 33 + cc];
        o.z = s[(p4 + 2) * 33 + cc]; o.w = s[(p4 + 3) * 33 + cc];
        __builtin_nontemporal_store(o, (f32x4*)&vimg[(b * 256 + c0 + cc) * 1024 + p0 + p4]);
        return;
    }

    // ---- GEMM + LIF, k-split ----
    int ks = t >> 8, tl = t & 255;
    int blk_n = blk >> 2, blk_c = blk & 3;
    int n0 = blk_n * 8, c0 = blk_c * 128;
    int c_t = tl & 31, n_l = tl >> 5;
    float* xs  = smem + ks * 2176;          // [32][68]
    float* wsb = smem + 4352 + ks * 4224;   // [32][132]

    float acc[8][4];
    #pragma unroll
    for (int b = 0; b < 8; ++b)
        #pragma unroll
        for (int j = 0; j < 4; ++j) acc[b][j] = 0.f;

    int um = tl >> 3, ukq = tl & 7;
    const float* gx1 = x + ((size_t)(um & 7) * 1024 + n0 + (um >> 3)) * 256 + ks * 128 + ukq * 4;
    const float* gx2 = gx1 + 4 * 256;
    float* lx1 = xs + (ukq * 4) * 68 + um;
    float* lx2 = lx1 + 32;
    const float* gw = Wqk + ((size_t)ks * 128 + (tl >> 5)) * 512 + c0 + (tl & 31) * 4;
    float* lw0 = wsb + (tl >> 5) * 132 + (tl & 31) * 4;

    f32x4 px0, px1, pw0, pw1, pw2, pw3;
    px0 = *(const f32x4*)(gx1);
    px1 = *(const f32x4*)(gx2);
    pw0 = *(const f32x4*)(gw);
    pw1 = *(const f32x4*)(gw + 8 * 512);
    pw2 = *(const f32x4*)(gw + 16 * 512);
    pw3 = *(const f32x4*)(gw + 24 * 512);

    for (int p = 0; p < 4; ++p) {
        #pragma unroll
        for (int j = 0; j < 4; ++j) { lx1[j * 68] = px0[j]; lx2[j * 68] = px1[j]; }
        *(f32x4*)(lw0)            = pw0;
        *(f32x4*)(lw0 + 8 * 132)  = pw1;
        *(f32x4*)(lw0 + 16 * 132) = pw2;
        *(f32x4*)(lw0 + 24 * 132) = pw3;
        __syncthreads();
        if (p < 3) {
            int ko = (p + 1) * 32;
            px0 = *(const f32x4*)(gx1 + ko);
            px1 = *(const f32x4*)(gx2 + ko);
            pw0 = *(const f32x4*)(gw + (ko + 0) * 512);
            pw1 = *(const f32x4*)(gw + (ko + 8) * 512);
            pw2 = *(const f32x4*)(gw + (ko + 16) * 512);
            pw3 = *(const f32x4*)(gw + (ko + 24) * 512);
        }
        #pragma unroll 8
        for (int kk = 0; kk < 32; ++kk) {
            f32x4 xa  = *(const f32x4*)(xs + kk * 68 + n_l * 8);
            f32x4 xb2 = *(const f32x4*)(xs + kk * 68 + n_l * 8 + 4);
            f32x4 w4  = *(const f32x4*)(wsb + kk * 132 + c_t * 4);
            #pragma unroll
            for (int b = 0; b < 4; ++b)
                #pragma unroll
                for (int j = 0; j < 4; ++j)
                    acc[b][j] = fmaf(xa[b], w4[j], acc[b][j]);
            #pragma unroll
            for (int b = 0; b < 4; ++b)
                #pragma unroll
                for (int j = 0; j < 4; ++j)
                    acc[b + 4][j] = fmaf(xb2[b], w4[j], acc[b + 4][j]);
        }
        __syncthreads();
    }

    // combine k-halves through LDS: comb[idx][tl], rows padded to 257
    float* comb = smem;
    if (ks == 1) {
        #pragma unroll
        for (int idx = 0; idx < 32; ++idx)
            comb[idx * 257 + tl] = acc[idx >> 2][idx & 3];
    }
    __syncthreads();
    if (ks == 0) {
        #pragma unroll
        for (int idx = 0; idx < 32; ++idx)
            acc[idx >> 2][idx & 3] += comb[idx * 257 + tl];
        // LIF scan over b (thread-local) + nibble pack
        float g = gamma[n0 + n_l], be = beta[n0 + n_l];
        f32x4 bq = *(const f32x4*)&bqk[c0 + c_t * 4];
        float v0 = 0.f, v1 = 0.f, v2 = 0.f, v3 = 0.f;
        #pragma unroll
        for (int b = 0; b < 8; ++b) {
            float a0 = (acc[b][0] + bq[0]) * g + be;
            float a1 = (acc[b][1] + bq[1]) * g + be;
            float a2 = (acc[b][2] + bq[2]) * g + be;
            float a3 = (acc[b][3] + bq[3]) * g + be;
            v0 = v0 + (a0 - v0) * 0.5f; v1 = v1 + (a1 - v1) * 0.5f;
            v2 = v2 + (a2 - v2) * 0.5f; v3 = v3 + (a3 - v3) * 0.5f;
            unsigned s0 = (v0 >= 1.f), s1 = (v1 >= 1.f), s2 = (v2 >= 1.f), s3 = (v3 >= 1.f);
            v0 = s0 ? 0.f : v0; v1 = s1 ? 0.f : v1;
            v2 = s2 ? 0.f : v2; v3 = s3 ? 0.f : v3;
            nib[n_l][c_t >> 3][c_t & 7][b] = s0 | (s1 << 1) | (s2 << 2) | (s3 << 3);
        }
    }
    __syncthreads();
    if (t < 256) {     // word assembly (group 0)
        int b = t & 7, hp = (t >> 3) & 3, nl = t >> 5;
        unsigned wd = 0;
        #pragma unroll
        for (int c8 = 0; c8 < 8; ++c8)
            wd |= nib[nl][hp][c8][b] << (4 * c8);
        unsigned h = (unsigned)((blk_c & 1) * 4 + hp);
        unsigned* dst = (blk_c < 2) ? mq : mk;
        dst[b * 8192 + h * 1024 + n0 + nl] = wd;
    }
}

// =====================================================================
// Phase 2 (256 thr):
//  blocks [0,256)    : partial kv + k-bit counts per (b,h,seg)
//  blocks [256,2304) : atten + qh/kh regen
// =====================================================================
__global__ __launch_bounds__(256) void phase2_kernel(
    const unsigned* __restrict__ mq, const unsigned* __restrict__ mk,
    const float* __restrict__ x, const float* __restrict__ tbl,
    float* __restrict__ qh, float* __restrict__ kh, float* __restrict__ att,
    float* __restrict__ kvp, float* __restrict__ kmp)
{
    int t = threadIdx.x;
    if (blockIdx.x < 256) {                // ---- kv partials ----
        int bh = blockIdx.x >> 2, seg = blockIdx.x & 3;
        int b = bh >> 3, h = bh & 7;
        int n0 = seg * 256;
        __shared__ float part[8][32];
        __shared__ float kr[64][36];
        __shared__ float vhs[64][33];
        int d = t & 31, ch = t >> 5;
        int sc = 0;
        for (int i = 0; i < 32; ++i)
            sc += (mk[bh * 1024 + n0 + ch * 32 + i] >> d) & 1u;
        part[ch][d] = (float)sc;
        __syncthreads();
        if (t < 32) {
            float cs = 0.f;
            #pragma unroll
            for (int j = 0; j < 8; ++j) cs += part[j][t];
            kmp[bh * 128 + seg * 32 + t] = cs;
        }
        float a0 = 0, a1 = 0, a2 = 0, a3 = 0;
        int e = t & 31, db = (t >> 5) * 4;
        for (int c0 = n0; c0 < n0 + 256; c0 += 64) {
            __syncthreads();
            #pragma unroll
            for (int i = 0; i < 8; ++i) {
                int f = t + i * 256;
                int nn = f >> 5, dd = f & 31;
                int n = c0 + nn;
                unsigned w = mk[bh * 1024 + n];
                float kd = 1.0f + (float)((w >> dd) & 1u);
                float ko = 1.0f + (float)((w >> (dd ^ 1)) & 1u);
                const float* cp = tbl + n * 256 + h * 32 + (dd & ~1);
                float cc2 = cp[0], ss2 = cp[1];
                kr[nn][dd] = (dd & 1) ? (ss2 * ko + cc2 * kd) : (cc2 * kd - ss2 * ko);
                vhs[nn][dd] = x[(b * 1024 + n) * 256 + h * 32 + dd];
            }
            __syncthreads();
            #pragma unroll 8
            for (int nn = 0; nn < 64; ++nn) {
                float ve = vhs[nn][e];
                float4 kk = *(const float4*)&kr[nn][db];
                a0 = fmaf(kk.x, ve, a0); a1 = fmaf(kk.y, ve, a1);
                a2 = fmaf(kk.z, ve, a2); a3 = fmaf(kk.w, ve, a3);
            }
        }
        float* dst = kvp + bh * 4096 + seg * 1024;
        dst[(db + 0) * 32 + e] = a0;
        dst[(db + 1) * 32 + e] = a1;
        dst[(db + 2) * 32 + e] = a2;
        dst[(db + 3) * 32 + e] = a3;
        return;
    }
    // ---- atten + qh/kh ----
    int blk = blockIdx.x - 256;
    int bh = blk >> 5;
    int tile = blk & 31;
    {
        int row = tile * 32 + (t >> 3);
        int d0 = (t & 7) * 4;
        unsigned wq = mq[bh * 1024 + row], wk = mk[bh * 1024 + row];
        f32x4 a, bb;
        a.x = 1.f + (float)((wq >> (d0 + 0)) & 1u);
        a.y = 1.f + (float)((wq >> (d0 + 1)) & 1u);
        a.z = 1.f + (float)((wq >> (d0 + 2)) & 1u);
        a.w = 1.f + (float)((wq >> (d0 + 3)) & 1u);
        bb.x = 1.f + (float)((wk >> (d0 + 0)) & 1u);
        bb.y = 1.f + (float)((wk >> (d0 + 1)) & 1u);
        bb.z = 1.f + (float)((wk >> (d0 + 2)) & 1u);
        bb.w = 1.f + (float)((wk >> (d0 + 3)) & 1u);
        __builtin_nontemporal_store(a,  (f32x4*)&qh[((bh * 1024 + row) << 5) + d0]);
        __builtin_nontemporal_store(bb, (f32x4*)&kh[((bh * 1024 + row) << 5) + d0]);
    }
    uint4 mm = ((const uint4*)(mk + bh * 1024))[t];
    float4 rr;
    rr.x = (float)__popc(mm.x); rr.y = (float)__popc(mm.y);
    rr.z = (float)__popc(mm.z); rr.w = (float)__popc(mm.w);
    float* base = att + ((size_t)bh * 1024 + (size_t)tile * 32) * 1024;
    for (int row = 0; row < 32; ++row) {
        unsigned mqw = mq[bh * 1024 + tile * 32 + row];
        float rq = 32.0f + (float)__popc(mqw);
        f32x4 o;
        o.x = rq + rr.x + (float)__popc(mqw & mm.x);
        o.y = rq + rr.y + (float)__popc(mqw & mm.y);
        o.z = rq + rr.z + (float)__popc(mqw & mm.z);
        o.w = rq + rr.w + (float)__popc(mqw & mm.w);
        __builtin_nontemporal_store(o, (f32x4*)(base + (size_t)row * 1024) + t);
    }
}

// ---------------- out = q_rope@kv * z + lepe ----------------
__global__ __launch_bounds__(256) void out_kernel(
    const unsigned* __restrict__ mq, const float* __restrict__ x,
    const float* __restrict__ tbl, const float* __restrict__ kvp,
    const float* __restrict__ kmp, const float* __restrict__ lw,
    const float* __restrict__ lb, float* __restrict__ out)
{
    int t = threadIdx.x;
    int bi = blockIdx.x;
    int bh = bi >> 3, sub = bi & 7;
    int pseg = sub >> 1, half = sub & 1;
    int b = bh >> 3, h = bh & 7;
    bool hy = (h < 4);
    int e = t & 31, p_l = t >> 5;
    int p = pseg * 8 + p_l;
    int q0 = half * 16;

    __shared__ float kvs[32][32];
    __shared__ float kmf[32];
    __shared__ float zs[128];
    const float inv = 1.0f / 1024.0f;
    #pragma unroll
    for (int i = 0; i < 4; ++i) {
        int f = t + i * 256;
        const float* kp = kvp + bh * 4096 + f;
        kvs[f >> 5][f & 31] = (kp[0] + kp[1024] + kp[2048] + kp[3072]) * inv;
    }
    if (t < 32) {
        const float* mp = kmp + bh * 128 + t;
        kmf[t] = 1.0f + (mp[0] + mp[32] + mp[64] + mp[96]) * inv;
    }
    __syncthreads();
    float S = 0.f;
    #pragma unroll
    for (int dd = 0; dd < 32; ++dd) S += kmf[dd];
    if (t < 128) {
        int pl2 = t >> 4, iq = t & 15;
        int pp = pseg * 8 + pl2, qq = q0 + iq;
        int n = hy ? (pp * 32 + qq) : (qq * 32 + pp);
        unsigned w = mq[bh * 1024 + n];
        float acc = S;
        #pragma unroll
        for (int dd = 0; dd < 32; ++dd)
            acc += (float)((w >> dd) & 1u) * kmf[dd];
        zs[t] = 1.0f / (acc + 1e-6f);
    }
    int n_ref = hy ? (p * 32) : p;
    const float* cp = tbl + n_ref * 256 + h * 32;
    float E[16], O[16], B = 0.f;
    #pragma unroll
    for (int j = 0; j < 16; ++j) {
        float c2 = cp[2 * j], s2 = cp[2 * j + 1];
        float K0 = kvs[2 * j][e], K1 = kvs[2 * j + 1][e];
        E[j] = c2 * K0 + s2 * K1;
        O[j] = c2 * K1 - s2 * K0;
        B += E[j] + O[j];
    }
    __syncthreads();
    int c = h * 32 + e;
    float w9[9];
    #pragma unroll
    for (int j = 0; j < 9; ++j) w9[j] = lw[c * 9 + j];
    float lbv = lb[c];
    const float* xb = x + (size_t)b * 262144 + c;
    auto ld = [&](int yy, int xx) -> float {
        if ((unsigned)yy > 31u || (unsigned)xx > 31u) return 0.f;
        return xb[(yy * 32 + xx) * 256];
    };
    if (hy) {
        int y = p;
        float Wm0 = ld(y - 1, q0 - 1), Wm1 = ld(y, q0 - 1), Wm2 = ld(y + 1, q0 - 1);
        float Wc0 = ld(y - 1, q0),     Wc1 = ld(y, q0),     Wc2 = ld(y + 1, q0);
        #pragma unroll 4
        for (int i = 0; i < 16; ++i) {
            int m = q0 + i;
            float Wp0 = ld(y - 1, m + 1), Wp1 = ld(y, m + 1), Wp2 = ld(y + 1, m + 1);
            int n = y * 32 + m;
            unsigned w = mq[bh * 1024 + n];
            float o = B;
            #pragma unroll
            for (int j = 0; j < 16; ++j) {
                o += (float)((w >> (2 * j)) & 1u) * E[j];
                o += (float)((w >> (2 * j + 1)) & 1u) * O[j];
            }
            o *= zs[p_l * 16 + i];
            float l = lbv;
            l = fmaf(w9[0], Wm0, l); l = fmaf(w9[1], Wc0, l); l = fmaf(w9[2], Wp0, l);
            l = fmaf(w9[3], Wm1, l); l = fmaf(w9[4], Wc1, l); l = fmaf(w9[5], Wp1, l);
            l = fmaf(w9[6], Wm2, l); l = fmaf(w9[7], Wc2, l); l = fmaf(w9[8], Wp2, l);
            __builtin_nontemporal_store(o + l, &out[((b * 1024 + n) << 8) + c]);
            Wm0 = Wc0; Wm1 = Wc1; Wm2 = Wc2;
            Wc0 = Wp0; Wc1 = Wp1; Wc2 = Wp2;
        }
    } else {
        int xx0 = p;
        float Wm0 = ld(q0 - 1, xx0 - 1), Wm1 = ld(q0 - 1, xx0), Wm2 = ld(q0 - 1, xx0 + 1);
        float Wc0 = ld(q0, xx0 - 1),     Wc1 = ld(q0, xx0),     Wc2 = ld(q0, xx0 + 1);
        #pragma unroll 4
        for (int i = 0; i < 16; ++i) {
            int m = q0 + i;
            float Wp0 = ld(m + 1, xx0 - 1), Wp1 = ld(m + 1, xx0), Wp2 = ld(m + 1, xx0 + 1);
            int n = m * 32 + xx0;
            unsigned w = mq[bh * 1024 + n];
            float o = B;
            #pragma unroll
            for (int j = 0; j < 16; ++j) {
                o += (float)((w >> (2 * j)) & 1u) * E[j];
                o += (float)((w >> (2 * j + 1)) & 1u) * O[j];
            }
            o *= zs[p_l * 16 + i];
            float l = lbv;
            l = fmaf(w9[0], Wm0, l); l = fmaf(w9[1], Wm1, l); l = fmaf(w9[2], Wm2, l);
            l = fmaf(w9[3], Wc0, l); l = fmaf(w9[4], Wc1, l); l = fmaf(w9[5], Wc2, l);
            l = fmaf(w9[6], Wp0, l); l = fmaf(w9[7], Wp1, l); l = fmaf(w9[8], Wp2, l);
            __builtin_nontemporal_store(o + l, &out[((b * 1024 + n) << 8) + c]);
            Wm0 = Wc0; Wm1 = Wc1; Wm2 = Wc2;
            Wc0 = Wp0; Wc1 = Wp1; Wc2 = Wp2;
        }
    }
}

extern "C" void kernel_launch(void* const* d_in, const int* in_sizes, int n_in,
                              void* d_out, int out_size, void* d_ws, size_t ws_size,
                              hipStream_t stream)
{
    const float* x     = (const float*)d_in[0];
    const float* Wqk   = (const float*)d_in[1];
    const float* bqk   = (const float*)d_in[2];
    const float* gamma = (const float*)d_in[3];
    const float* beta  = (const float*)d_in[4];
    const float* lw    = (const float*)d_in[5];
    const float* lb    = (const float*)d_in[6];
    float* out = (float*)d_out;
    unsigned* ws = (unsigned*)d_ws;
    unsigned* mq = ws + WS_MQ;
    unsigned* mk = ws + WS_MK;
    float* tbl  = (float*)(ws + WS_TBL);
    float* kvp  = (float*)(ws + WS_KVP);
    float* kmp  = (float*)(ws + WS_KMP);

    hipLaunchKernelGGL(phase1_kernel, dim3(1792), dim3(512), 0, stream,
                       x, Wqk, bqk, gamma, beta, mq, mk, out + OFF_VIMG, tbl);
    hipLaunchKernelGGL(phase2_kernel, dim3(2304), dim3(256), 0, stream,
                       mq, mk, x, tbl, out + OFF_QH, out + OFF_KH, out + OFF_ATT,
                       kvp, kmp);
    hipLaunchKernelGGL(out_kernel, dim3(512), dim3(256), 0, stream,
                       mq, x, tbl, kvp, kmp, lw, lb, out + OFF_OUT);
}

// Round 5
// 102.240 us; speedup vs baseline: 3.4498x; 1.0528x over previous
//
#include <hip/hip_runtime.h>
#include <cstdint>
#include <cstddef>

// Outputs concat (f32): out(8,1024,256) qh(8,8,1024,32) kh(8,8,1024,32)
//                       v_img(8,256,32,32) atten(8,8,1024,1024)
#define OFF_OUT   0
#define OFF_QH    2097152
#define OFF_KH    4194304
#define OFF_VIMG  6291456
#define OFF_ATT   8388608

// ws layout (4-byte units)
#define WS_MQ   0        // 8*8*1024 u32
#define WS_MK   65536
#define WS_TBL  131072   // 1024*128*2 f32 (cos,sin interleaved)
#define WS_KVP  393216   // 64 bh * 4 seg * 32*32 f32 partial kv
#define WS_KMP  655360   // 64 bh * 4 seg * 32 f32 partial k-bit counts

typedef float f32x4 __attribute__((ext_vector_type(4)));

// ---- fused GEMM+BN+LIF+pack for one (blk_n, blk_c) tile; 512 thr, k-split ----
__device__ __forceinline__ void gemm_lif_512(
    const float* __restrict__ x, const float* __restrict__ Wqk,
    const float* __restrict__ bqk, const float* __restrict__ gamma,
    const float* __restrict__ beta, unsigned* __restrict__ mq,
    unsigned* __restrict__ mk, float* smem, unsigned* nib,
    int blk_n, int blk_c, int t)
{
    int ks = t >> 8, tl = t & 255;
    int n0 = blk_n * 8, c0 = blk_c * 128;
    int c_t = tl & 31, n_l = tl >> 5;
    float* xs  = smem + ks * 2176;          // [32][68]
    float* wsb = smem + 4352 + ks * 4224;   // [32][132]

    float acc[8][4];
    #pragma unroll
    for (int b = 0; b < 8; ++b)
        #pragma unroll
        for (int j = 0; j < 4; ++j) acc[b][j] = 0.f;

    int um = tl >> 3, ukq = tl & 7;
    const float* gx1 = x + ((size_t)(um & 7) * 1024 + n0 + (um >> 3)) * 256 + ks * 128 + ukq * 4;
    const float* gx2 = gx1 + 4 * 256;
    float* lx1 = xs + (ukq * 4) * 68 + um;
    float* lx2 = lx1 + 32;
    const float* gw = Wqk + ((size_t)ks * 128 + (tl >> 5)) * 512 + c0 + (tl & 31) * 4;
    float* lw0 = wsb + (tl >> 5) * 132 + (tl & 31) * 4;

    f32x4 px0, px1, pw0, pw1, pw2, pw3;
    px0 = *(const f32x4*)(gx1);
    px1 = *(const f32x4*)(gx2);
    pw0 = *(const f32x4*)(gw);
    pw1 = *(const f32x4*)(gw + 8 * 512);
    pw2 = *(const f32x4*)(gw + 16 * 512);
    pw3 = *(const f32x4*)(gw + 24 * 512);

    for (int p = 0; p < 4; ++p) {
        #pragma unroll
        for (int j = 0; j < 4; ++j) { lx1[j * 68] = px0[j]; lx2[j * 68] = px1[j]; }
        *(f32x4*)(lw0)            = pw0;
        *(f32x4*)(lw0 + 8 * 132)  = pw1;
        *(f32x4*)(lw0 + 16 * 132) = pw2;
        *(f32x4*)(lw0 + 24 * 132) = pw3;
        __syncthreads();
        if (p < 3) {
            int ko = (p + 1) * 32;
            px0 = *(const f32x4*)(gx1 + ko);
            px1 = *(const f32x4*)(gx2 + ko);
            pw0 = *(const f32x4*)(gw + (ko + 0) * 512);
            pw1 = *(const f32x4*)(gw + (ko + 8) * 512);
            pw2 = *(const f32x4*)(gw + (ko + 16) * 512);
            pw3 = *(const f32x4*)(gw + (ko + 24) * 512);
        }
        #pragma unroll 8
        for (int kk = 0; kk < 32; ++kk) {
            f32x4 xa  = *(const f32x4*)(xs + kk * 68 + n_l * 8);
            f32x4 xb2 = *(const f32x4*)(xs + kk * 68 + n_l * 8 + 4);
            f32x4 w4  = *(const f32x4*)(wsb + kk * 132 + c_t * 4);
            #pragma unroll
            for (int b = 0; b < 4; ++b)
                #pragma unroll
                for (int j = 0; j < 4; ++j)
                    acc[b][j] = fmaf(xa[b], w4[j], acc[b][j]);
            #pragma unroll
            for (int b = 0; b < 4; ++b)
                #pragma unroll
                for (int j = 0; j < 4; ++j)
                    acc[b + 4][j] = fmaf(xb2[b], w4[j], acc[b + 4][j]);
        }
        __syncthreads();
    }

    // combine k-halves through LDS: comb[idx][tl], rows padded to 257
    float* comb = smem;
    if (ks == 1) {
        #pragma unroll
        for (int idx = 0; idx < 32; ++idx)
            comb[idx * 257 + tl] = acc[idx >> 2][idx & 3];
    }
    __syncthreads();
    if (ks == 0) {
        #pragma unroll
        for (int idx = 0; idx < 32; ++idx)
            acc[idx >> 2][idx & 3] += comb[idx * 257 + tl];
        float g = gamma[n0 + n_l], be = beta[n0 + n_l];
        f32x4 bq = *(const f32x4*)&bqk[c0 + c_t * 4];
        float v0 = 0.f, v1 = 0.f, v2 = 0.f, v3 = 0.f;
        #pragma unroll
        for (int b = 0; b < 8; ++b) {
            float a0 = (acc[b][0] + bq[0]) * g + be;
            float a1 = (acc[b][1] + bq[1]) * g + be;
            float a2 = (acc[b][2] + bq[2]) * g + be;
            float a3 = (acc[b][3] + bq[3]) * g + be;
            v0 = v0 + (a0 - v0) * 0.5f; v1 = v1 + (a1 - v1) * 0.5f;
            v2 = v2 + (a2 - v2) * 0.5f; v3 = v3 + (a3 - v3) * 0.5f;
            unsigned s0 = (v0 >= 1.f), s1 = (v1 >= 1.f), s2 = (v2 >= 1.f), s3 = (v3 >= 1.f);
            v0 = s0 ? 0.f : v0; v1 = s1 ? 0.f : v1;
            v2 = s2 ? 0.f : v2; v3 = s3 ? 0.f : v3;
            nib[n_l * 256 + (c_t >> 3) * 64 + (c_t & 7) * 8 + b] =
                s0 | (s1 << 1) | (s2 << 2) | (s3 << 3);
        }
    }
    __syncthreads();
    if (t < 256) {
        int b = t & 7, hp = (t >> 3) & 3, nl = t >> 5;
        unsigned wd = 0;
        #pragma unroll
        for (int c8 = 0; c8 < 8; ++c8)
            wd |= nib[nl * 256 + hp * 64 + c8 * 8 + b] << (4 * c8);
        unsigned h = (unsigned)((blk_c & 1) * 4 + hp);
        unsigned* dst = (blk_c < 2) ? mq : mk;
        dst[b * 8192 + h * 1024 + n0 + nl] = wd;
    }
}

// =====================================================================
// Phase A (512 thr, 1536 blocks):
//  [0,256)    : GEMM blk_c in {2,3}  -> mk
//  [256,1280) : vimg transpose, 2 tiles/block
//  [1280,1536): rope table
// =====================================================================
__global__ __launch_bounds__(512) void phaseA_kernel(
    const float* __restrict__ x, const float* __restrict__ Wqk,
    const float* __restrict__ bqk, const float* __restrict__ gamma,
    const float* __restrict__ beta, unsigned* __restrict__ mq,
    unsigned* __restrict__ mk, float* __restrict__ vimg,
    float* __restrict__ tbl)
{
    __shared__ float smem[12800];
    __shared__ unsigned nib[2048];
    int t = threadIdx.x;
    int blk = blockIdx.x;
    if (blk < 256) {
        gemm_lif_512(x, Wqk, bqk, gamma, beta, mq, mk, smem, nib,
                     blk >> 1, 2 + (blk & 1), t);
        return;
    }
    if (blk >= 1280) {                     // ---- rope table ----
        int id = (blk - 1280) * 512 + t;   // 131072 total
        int j = id & 127, n = id >> 7;
        int i = (j < 64) ? j : j - 64;
        float th = powf(10000.0f, -(float)i * (1.0f / 64.0f));
        float pos = (float)((j < 64) ? (n >> 5) : (n & 31));
        float ang = pos * th;
        tbl[n * 256 + j * 2]     = cosf(ang);
        tbl[n * 256 + j * 2 + 1] = sinf(ang);
        return;
    }
    // ---- vimg transpose ----
    int tile = (blk - 256) * 2 + (t >> 8);
    int st = t & 255;
    float* s = smem + (t >> 8) * 1056; // [32][33]
    int b = tile >> 8, ti = tile & 255;
    int p0 = (ti >> 3) * 32, c0 = (ti & 7) * 32;
    int row = st >> 3, c4 = (st & 7) * 4;
    const float4 vl = *(const float4*)&x[(b * 1024 + p0 + row) * 256 + c0 + c4];
    s[row * 33 + c4 + 0] = vl.x; s[row * 33 + c4 + 1] = vl.y;
    s[row * 33 + c4 + 2] = vl.z; s[row * 33 + c4 + 3] = vl.w;
    __syncthreads();
    int cc = st >> 3, p4 = (st & 7) * 4;
    f32x4 o;
    o.x = s[(p4 + 0) * 33 + cc]; o.y = s[(p4 + 1) * 33 + cc];
    o.z = s[(p4 + 2) * 33 + cc]; o.w = s[(p4 + 3) * 33 + cc];
    __builtin_nontemporal_store(o, (f32x4*)&vimg[(b * 256 + c0 + cc) * 1024 + p0 + p4]);
}

// =====================================================================
// Phase B (512 thr, 384 blocks):
//  [0,256)   : GEMM blk_c in {0,1}  -> mq
//  [256,384) : kv partials + k-bit counts, 2 units/block (needs mk, tbl)
// =====================================================================
__global__ __launch_bounds__(512) void phaseB_kernel(
    const float* __restrict__ x, const float* __restrict__ Wqk,
    const float* __restrict__ bqk, const float* __restrict__ gamma,
    const float* __restrict__ beta, unsigned* __restrict__ mq,
    unsigned* __restrict__ mk, const float* __restrict__ tbl,
    float* __restrict__ kvp, float* __restrict__ kmp)
{
    __shared__ float smem[12800];
    __shared__ unsigned nib[2048];
    int t = threadIdx.x;
    int blk = blockIdx.x;
    if (blk < 256) {
        gemm_lif_512(x, Wqk, bqk, gamma, beta, mq, mk, smem, nib,
                     blk >> 1, blk & 1, t);
        return;
    }
    // ---- kv partials: 2 independent 256-thr units (identical barrier counts) ----
    int ks2 = t >> 8, tl = t & 255;
    int unit = (blk - 256) * 2 + ks2;      // 0..255
    int bh = unit >> 2, seg = unit & 3;
    int b = bh >> 3, h = bh & 7;
    int n0 = seg * 256;
    float* kr   = smem + ks2 * 4800;       // [64][36]
    float* vhs  = kr + 2304;               // [64][33]
    float* part = kr + 4416;               // [8][32]
    int d = tl & 31, ch = tl >> 5;
    int sc = 0;
    for (int i = 0; i < 32; ++i)
        sc += (mk[bh * 1024 + n0 + ch * 32 + i] >> d) & 1u;
    part[ch * 32 + d] = (float)sc;
    __syncthreads();
    if (tl < 32) {
        float cs = 0.f;
        #pragma unroll
        for (int j = 0; j < 8; ++j) cs += part[j * 32 + tl];
        kmp[bh * 128 + seg * 32 + tl] = cs;
    }
    float a0 = 0, a1 = 0, a2 = 0, a3 = 0;
    int e = tl & 31, db = (tl >> 5) * 4;
    for (int c0 = n0; c0 < n0 + 256; c0 += 64) {
        __syncthreads();
        #pragma unroll
        for (int i = 0; i < 8; ++i) {
            int f = tl + i * 256;
            int nn = f >> 5, dd = f & 31;
            int n = c0 + nn;
            unsigned w = mk[bh * 1024 + n];
            float kd = 1.0f + (float)((w >> dd) & 1u);
            float ko = 1.0f + (float)((w >> (dd ^ 1)) & 1u);
            const float* cp = tbl + n * 256 + h * 32 + (dd & ~1);
            float cc2 = cp[0], ss2 = cp[1];
            kr[nn * 36 + dd] = (dd & 1) ? (ss2 * ko + cc2 * kd) : (cc2 * kd - ss2 * ko);
            vhs[nn * 33 + dd] = x[(b * 1024 + n) * 256 + h * 32 + dd];
        }
        __syncthreads();
        #pragma unroll 8
        for (int nn = 0; nn < 64; ++nn) {
            float ve = vhs[nn * 33 + e];
            float4 kk = *(const float4*)&kr[nn * 36 + db];
            a0 = fmaf(kk.x, ve, a0); a1 = fmaf(kk.y, ve, a1);
            a2 = fmaf(kk.z, ve, a2); a3 = fmaf(kk.w, ve, a3);
        }
    }
    float* dst = kvp + bh * 4096 + seg * 1024;
    dst[(db + 0) * 32 + e] = a0;
    dst[(db + 1) * 32 + e] = a1;
    dst[(db + 2) * 32 + e] = a2;
    dst[(db + 3) * 32 + e] = a3;
}

// =====================================================================
// Phase C (256 thr, 2560 blocks): all heavy writes
//  [0,512)    : out = q_rope@kv * z + lepe
//  [512,2560) : atten + qh/kh regen
// =====================================================================
__global__ __launch_bounds__(256) void phaseC_kernel(
    const unsigned* __restrict__ mq, const unsigned* __restrict__ mk,
    const float* __restrict__ x, const float* __restrict__ tbl,
    const float* __restrict__ kvp, const float* __restrict__ kmp,
    const float* __restrict__ lw, const float* __restrict__ lb,
    float* __restrict__ outbase)
{
    int t = threadIdx.x;
    if (blockIdx.x >= 512) {               // ---- atten + qh/kh ----
        int blk = blockIdx.x - 512;
        int bh = blk >> 5;
        int tile = blk & 31;
        float* qh = outbase + OFF_QH;
        float* kh = outbase + OFF_KH;
        float* att = outbase + OFF_ATT;
        {
            int row = tile * 32 + (t >> 3);
            int d0 = (t & 7) * 4;
            unsigned wq = mq[bh * 1024 + row], wk = mk[bh * 1024 + row];
            f32x4 a, bb;
            a.x = 1.f + (float)((wq >> (d0 + 0)) & 1u);
            a.y = 1.f + (float)((wq >> (d0 + 1)) & 1u);
            a.z = 1.f + (float)((wq >> (d0 + 2)) & 1u);
            a.w = 1.f + (float)((wq >> (d0 + 3)) & 1u);
            bb.x = 1.f + (float)((wk >> (d0 + 0)) & 1u);
            bb.y = 1.f + (float)((wk >> (d0 + 1)) & 1u);
            bb.z = 1.f + (float)((wk >> (d0 + 2)) & 1u);
            bb.w = 1.f + (float)((wk >> (d0 + 3)) & 1u);
            __builtin_nontemporal_store(a,  (f32x4*)&qh[((bh * 1024 + row) << 5) + d0]);
            __builtin_nontemporal_store(bb, (f32x4*)&kh[((bh * 1024 + row) << 5) + d0]);
        }
        uint4 mm = ((const uint4*)(mk + bh * 1024))[t];
        float4 rr;
        rr.x = (float)__popc(mm.x); rr.y = (float)__popc(mm.y);
        rr.z = (float)__popc(mm.z); rr.w = (float)__popc(mm.w);
        float* base = att + ((size_t)bh * 1024 + (size_t)tile * 32) * 1024;
        for (int row = 0; row < 32; ++row) {
            unsigned mqw = mq[bh * 1024 + tile * 32 + row];
            float rq = 32.0f + (float)__popc(mqw);
            f32x4 o;
            o.x = rq + rr.x + (float)__popc(mqw & mm.x);
            o.y = rq + rr.y + (float)__popc(mqw & mm.y);
            o.z = rq + rr.z + (float)__popc(mqw & mm.z);
            o.w = rq + rr.w + (float)__popc(mqw & mm.w);
            __builtin_nontemporal_store(o, (f32x4*)(base + (size_t)row * 1024) + t);
        }
        return;
    }
    // ---- out ----
    int bi = blockIdx.x;
    int bh = bi >> 3, sub = bi & 7;
    int pseg = sub >> 1, half = sub & 1;
    int b = bh >> 3, h = bh & 7;
    bool hy = (h < 4);
    int e = t & 31, p_l = t >> 5;
    int p = pseg * 8 + p_l;
    int q0 = half * 16;
    float* out = outbase + OFF_OUT;

    __shared__ float kvs[32][32];
    __shared__ float kmf[32];
    __shared__ float zs[128];
    const float inv = 1.0f / 1024.0f;
    #pragma unroll
    for (int i = 0; i < 4; ++i) {
        int f = t + i * 256;
        const float* kp = kvp + bh * 4096 + f;
        kvs[f >> 5][f & 31] = (kp[0] + kp[1024] + kp[2048] + kp[3072]) * inv;
    }
    if (t < 32) {
        const float* mp = kmp + bh * 128 + t;
        kmf[t] = 1.0f + (mp[0] + mp[32] + mp[64] + mp[96]) * inv;
    }
    __syncthreads();
    float S = 0.f;
    #pragma unroll
    for (int dd = 0; dd < 32; ++dd) S += kmf[dd];
    if (t < 128) {
        int pl2 = t >> 4, iq = t & 15;
        int pp = pseg * 8 + pl2, qq = q0 + iq;
        int n = hy ? (pp * 32 + qq) : (qq * 32 + pp);
        unsigned w = mq[bh * 1024 + n];
        float acc = S;
        #pragma unroll
        for (int dd = 0; dd < 32; ++dd)
            acc += (float)((w >> dd) & 1u) * kmf[dd];
        zs[t] = 1.0f / (acc + 1e-6f);
    }
    int n_ref = hy ? (p * 32) : p;
    const float* cp = tbl + n_ref * 256 + h * 32;
    float E[16], O[16], B = 0.f;
    #pragma unroll
    for (int j = 0; j < 16; ++j) {
        float c2 = cp[2 * j], s2 = cp[2 * j + 1];
        float K0 = kvs[2 * j][e], K1 = kvs[2 * j + 1][e];
        E[j] = c2 * K0 + s2 * K1;
        O[j] = c2 * K1 - s2 * K0;
        B += E[j] + O[j];
    }
    __syncthreads();
    int c = h * 32 + e;
    float w9[9];
    #pragma unroll
    for (int j = 0; j < 9; ++j) w9[j] = lw[c * 9 + j];
    float lbv = lb[c];
    const float* xb = x + (size_t)b * 262144 + c;
    auto ld = [&](int yy, int xx) -> float {
        if ((unsigned)yy > 31u || (unsigned)xx > 31u) return 0.f;
        return xb[(yy * 32 + xx) * 256];
    };
    if (hy) {
        int y = p;
        float Wm0 = ld(y - 1, q0 - 1), Wm1 = ld(y, q0 - 1), Wm2 = ld(y + 1, q0 - 1);
        float Wc0 = ld(y - 1, q0),     Wc1 = ld(y, q0),     Wc2 = ld(y + 1, q0);
        #pragma unroll 4
        for (int i = 0; i < 16; ++i) {
            int m = q0 + i;
            float Wp0 = ld(y - 1, m + 1), Wp1 = ld(y, m + 1), Wp2 = ld(y + 1, m + 1);
            int n = y * 32 + m;
            unsigned w = mq[bh * 1024 + n];
            float o = B;
            #pragma unroll
            for (int j = 0; j < 16; ++j) {
                o += (float)((w >> (2 * j)) & 1u) * E[j];
                o += (float)((w >> (2 * j + 1)) & 1u) * O[j];
            }
            o *= zs[p_l * 16 + i];
            float l = lbv;
            l = fmaf(w9[0], Wm0, l); l = fmaf(w9[1], Wc0, l); l = fmaf(w9[2], Wp0, l);
            l = fmaf(w9[3], Wm1, l); l = fmaf(w9[4], Wc1, l); l = fmaf(w9[5], Wp1, l);
            l = fmaf(w9[6], Wm2, l); l = fmaf(w9[7], Wc2, l); l = fmaf(w9[8], Wp2, l);
            __builtin_nontemporal_store(o + l, &out[((b * 1024 + n) << 8) + c]);
            Wm0 = Wc0; Wm1 = Wc1; Wm2 = Wc2;
            Wc0 = Wp0; Wc1 = Wp1; Wc2 = Wp2;
        }
    } else {
        int xx0 = p;
        float Wm0 = ld(q0 - 1, xx0 - 1), Wm1 = ld(q0 - 1, xx0), Wm2 = ld(q0 - 1, xx0 + 1);
        float Wc0 = ld(q0, xx0 - 1),     Wc1 = ld(q0, xx0),     Wc2 = ld(q0, xx0 + 1);
        #pragma unroll 4
        for (int i = 0; i < 16; ++i) {
            int m = q0 + i;
            float Wp0 = ld(m + 1, xx0 - 1), Wp1 = ld(m + 1, xx0), Wp2 = ld(m + 1, xx0 + 1);
            int n = m * 32 + xx0;
            unsigned w = mq[bh * 1024 + n];
            float o = B;
            #pragma unroll
            for (int j = 0; j < 16; ++j) {
                o += (float)((w >> (2 * j)) & 1u) * E[j];
                o += (float)((w >> (2 * j + 1)) & 1u) * O[j];
            }
            o *= zs[p_l * 16 + i];
            float l = lbv;
            l = fmaf(w9[0], Wm0, l); l = fmaf(w9[1], Wm1, l); l = fmaf(w9[2], Wm2, l);
            l = fmaf(w9[3], Wc0, l); l = fmaf(w9[4], Wc1, l); l = fmaf(w9[5], Wc2, l);
            l = fmaf(w9[6], Wp0, l); l = fmaf(w9[7], Wp1, l); l = fmaf(w9[8], Wp2, l);
            __builtin_nontemporal_store(o + l, &out[((b * 1024 + n) << 8) + c]);
            Wm0 = Wc0; Wm1 = Wc1; Wm2 = Wc2;
            Wc0 = Wp0; Wc1 = Wp1; Wc2 = Wp2;
        }
    }
}

extern "C" void kernel_launch(void* const* d_in, const int* in_sizes, int n_in,
                              void* d_out, int out_size, void* d_ws, size_t ws_size,
                              hipStream_t stream)
{
    const float* x     = (const float*)d_in[0];
    const float* Wqk   = (const float*)d_in[1];
    const float* bqk   = (const float*)d_in[2];
    const float* gamma = (const float*)d_in[3];
    const float* beta  = (const float*)d_in[4];
    const float* lw    = (const float*)d_in[5];
    const float* lb    = (const float*)d_in[6];
    float* out = (float*)d_out;
    unsigned* ws = (unsigned*)d_ws;
    unsigned* mq = ws + WS_MQ;
    unsigned* mk = ws + WS_MK;
    float* tbl  = (float*)(ws + WS_TBL);
    float* kvp  = (float*)(ws + WS_KVP);
    float* kmp  = (float*)(ws + WS_KMP);

    hipLaunchKernelGGL(phaseA_kernel, dim3(1536), dim3(512), 0, stream,
                       x, Wqk, bqk, gamma, beta, mq, mk, out + OFF_VIMG, tbl);
    hipLaunchKernelGGL(phaseB_kernel, dim3(384), dim3(512), 0, stream,
                       x, Wqk, bqk, gamma, beta, mq, mk, tbl, kvp, kmp);
    hipLaunchKernelGGL(phaseC_kernel, dim3(2560), dim3(256), 0, stream,
                       mq, mk, x, tbl, kvp, kmp, lw, lb, out);
}

// Round 6
// 95.353 us; speedup vs baseline: 3.6990x; 1.0722x over previous
//
#include <hip/hip_runtime.h>
#include <cstdint>
#include <cstddef>

// Outputs concat (f32): out(8,1024,256) qh(8,8,1024,32) kh(8,8,1024,32)
//                       v_img(8,256,32,32) atten(8,8,1024,1024)
#define OFF_OUT   0
#define OFF_QH    2097152
#define OFF_KH    4194304
#define OFF_VIMG  6291456
#define OFF_ATT   8388608

// ws layout (4-byte units)
#define WS_MQ   0        // 8*8*1024 u32
#define WS_MK   65536
#define WS_TBL  131072   // 1024*128*2 f32 (cos,sin interleaved)
#define WS_KVP  393216   // 64 bh * 4 seg * 32*32 f32 partial kv
#define WS_KMP  655360   // 64 bh * 4 seg * 32 f32 partial k-bit counts

typedef float f32x4 __attribute__((ext_vector_type(4)));

// ---- fused GEMM+BN+LIF+pack for one (blk_n, blk_c) tile; 512 thr, k-split ----
__device__ __forceinline__ void gemm_lif_512(
    const float* __restrict__ x, const float* __restrict__ Wqk,
    const float* __restrict__ bqk, const float* __restrict__ gamma,
    const float* __restrict__ beta, unsigned* __restrict__ mq,
    unsigned* __restrict__ mk, float* smem, unsigned* nib,
    int blk_n, int blk_c, int t)
{
    int ks = t >> 8, tl = t & 255;
    int n0 = blk_n * 8, c0 = blk_c * 128;
    int c_t = tl & 31, n_l = tl >> 5;
    float* xs  = smem + ks * 2176;          // [32][68]
    float* wsb = smem + 4352 + ks * 4224;   // [32][132]

    float acc[8][4];
    #pragma unroll
    for (int b = 0; b < 8; ++b)
        #pragma unroll
        for (int j = 0; j < 4; ++j) acc[b][j] = 0.f;

    int um = tl >> 3, ukq = tl & 7;
    const float* gx1 = x + ((size_t)(um & 7) * 1024 + n0 + (um >> 3)) * 256 + ks * 128 + ukq * 4;
    const float* gx2 = gx1 + 4 * 256;
    float* lx1 = xs + (ukq * 4) * 68 + um;
    float* lx2 = lx1 + 32;
    const float* gw = Wqk + ((size_t)ks * 128 + (tl >> 5)) * 512 + c0 + (tl & 31) * 4;
    float* lw0 = wsb + (tl >> 5) * 132 + (tl & 31) * 4;

    f32x4 px0, px1, pw0, pw1, pw2, pw3;
    px0 = *(const f32x4*)(gx1);
    px1 = *(const f32x4*)(gx2);
    pw0 = *(const f32x4*)(gw);
    pw1 = *(const f32x4*)(gw + 8 * 512);
    pw2 = *(const f32x4*)(gw + 16 * 512);
    pw3 = *(const f32x4*)(gw + 24 * 512);

    for (int p = 0; p < 4; ++p) {
        #pragma unroll
        for (int j = 0; j < 4; ++j) { lx1[j * 68] = px0[j]; lx2[j * 68] = px1[j]; }
        *(f32x4*)(lw0)            = pw0;
        *(f32x4*)(lw0 + 8 * 132)  = pw1;
        *(f32x4*)(lw0 + 16 * 132) = pw2;
        *(f32x4*)(lw0 + 24 * 132) = pw3;
        __syncthreads();
        if (p < 3) {
            int ko = (p + 1) * 32;
            px0 = *(const f32x4*)(gx1 + ko);
            px1 = *(const f32x4*)(gx2 + ko);
            pw0 = *(const f32x4*)(gw + (ko + 0) * 512);
            pw1 = *(const f32x4*)(gw + (ko + 8) * 512);
            pw2 = *(const f32x4*)(gw + (ko + 16) * 512);
            pw3 = *(const f32x4*)(gw + (ko + 24) * 512);
        }
        #pragma unroll 8
        for (int kk = 0; kk < 32; ++kk) {
            f32x4 xa  = *(const f32x4*)(xs + kk * 68 + n_l * 8);
            f32x4 xb2 = *(const f32x4*)(xs + kk * 68 + n_l * 8 + 4);
            f32x4 w4  = *(const f32x4*)(wsb + kk * 132 + c_t * 4);
            #pragma unroll
            for (int b = 0; b < 4; ++b)
                #pragma unroll
                for (int j = 0; j < 4; ++j)
                    acc[b][j] = fmaf(xa[b], w4[j], acc[b][j]);
            #pragma unroll
            for (int b = 0; b < 4; ++b)
                #pragma unroll
                for (int j = 0; j < 4; ++j)
                    acc[b + 4][j] = fmaf(xb2[b], w4[j], acc[b + 4][j]);
        }
        __syncthreads();
    }

    // combine k-halves through LDS: comb[idx][tl], rows padded to 257
    float* comb = smem;
    if (ks == 1) {
        #pragma unroll
        for (int idx = 0; idx < 32; ++idx)
            comb[idx * 257 + tl] = acc[idx >> 2][idx & 3];
    }
    __syncthreads();
    if (ks == 0) {
        #pragma unroll
        for (int idx = 0; idx < 32; ++idx)
            acc[idx >> 2][idx & 3] += comb[idx * 257 + tl];
        float g = gamma[n0 + n_l], be = beta[n0 + n_l];
        f32x4 bq = *(const f32x4*)&bqk[c0 + c_t * 4];
        float v0 = 0.f, v1 = 0.f, v2 = 0.f, v3 = 0.f;
        #pragma unroll
        for (int b = 0; b < 8; ++b) {
            float a0 = (acc[b][0] + bq[0]) * g + be;
            float a1 = (acc[b][1] + bq[1]) * g + be;
            float a2 = (acc[b][2] + bq[2]) * g + be;
            float a3 = (acc[b][3] + bq[3]) * g + be;
            v0 = v0 + (a0 - v0) * 0.5f; v1 = v1 + (a1 - v1) * 0.5f;
            v2 = v2 + (a2 - v2) * 0.5f; v3 = v3 + (a3 - v3) * 0.5f;
            unsigned s0 = (v0 >= 1.f), s1 = (v1 >= 1.f), s2 = (v2 >= 1.f), s3 = (v3 >= 1.f);
            v0 = s0 ? 0.f : v0; v1 = s1 ? 0.f : v1;
            v2 = s2 ? 0.f : v2; v3 = s3 ? 0.f : v3;
            nib[n_l * 256 + (c_t >> 3) * 64 + (c_t & 7) * 8 + b] =
                s0 | (s1 << 1) | (s2 << 2) | (s3 << 3);
        }
    }
    __syncthreads();
    if (t < 256) {
        int b = t & 7, hp = (t >> 3) & 3, nl = t >> 5;
        unsigned wd = 0;
        #pragma unroll
        for (int c8 = 0; c8 < 8; ++c8)
            wd |= nib[nl * 256 + hp * 64 + c8 * 8 + b] << (4 * c8);
        unsigned h = (unsigned)((blk_c & 1) * 4 + hp);
        unsigned* dst = (blk_c < 2) ? mq : mk;
        dst[b * 8192 + h * 1024 + n0 + nl] = wd;
    }
}

// =====================================================================
// Phase A (512 thr, 1536 blocks):
//  [0,256)    : GEMM blk_c in {2,3}  -> mk
//  [256,1280) : vimg transpose, 2 tiles/block
//  [1280,1536): rope table
// =====================================================================
__global__ __launch_bounds__(512) void phaseA_kernel(
    const float* __restrict__ x, const float* __restrict__ Wqk,
    const float* __restrict__ bqk, const float* __restrict__ gamma,
    const float* __restrict__ beta, unsigned* __restrict__ mq,
    unsigned* __restrict__ mk, float* __restrict__ vimg,
    float* __restrict__ tbl)
{
    __shared__ float smem[12800];
    __shared__ unsigned nib[2048];
    int t = threadIdx.x;
    int blk = blockIdx.x;
    if (blk < 256) {
        gemm_lif_512(x, Wqk, bqk, gamma, beta, mq, mk, smem, nib,
                     blk >> 1, 2 + (blk & 1), t);
        return;
    }
    if (blk >= 1280) {                     // ---- rope table ----
        int id = (blk - 1280) * 512 + t;   // 131072 total
        int j = id & 127, n = id >> 7;
        int i = (j < 64) ? j : j - 64;
        float th = powf(10000.0f, -(float)i * (1.0f / 64.0f));
        float pos = (float)((j < 64) ? (n >> 5) : (n & 31));
        float ang = pos * th;
        tbl[n * 256 + j * 2]     = cosf(ang);
        tbl[n * 256 + j * 2 + 1] = sinf(ang);
        return;
    }
    // ---- vimg transpose ----
    int tile = (blk - 256) * 2 + (t >> 8);
    int st = t & 255;
    float* s = smem + (t >> 8) * 1056; // [32][33]
    int b = tile >> 8, ti = tile & 255;
    int p0 = (ti >> 3) * 32, c0 = (ti & 7) * 32;
    int row = st >> 3, c4 = (st & 7) * 4;
    const float4 vl = *(const float4*)&x[(b * 1024 + p0 + row) * 256 + c0 + c4];
    s[row * 33 + c4 + 0] = vl.x; s[row * 33 + c4 + 1] = vl.y;
    s[row * 33 + c4 + 2] = vl.z; s[row * 33 + c4 + 3] = vl.w;
    __syncthreads();
    int cc = st >> 3, p4 = (st & 7) * 4;
    f32x4 o;
    o.x = s[(p4 + 0) * 33 + cc]; o.y = s[(p4 + 1) * 33 + cc];
    o.z = s[(p4 + 2) * 33 + cc]; o.w = s[(p4 + 3) * 33 + cc];
    *(f32x4*)&vimg[(b * 256 + c0 + cc) * 1024 + p0 + p4] = o;
}

// =====================================================================
// Phase B (512 thr, 384 blocks):
//  [0,256)   : GEMM blk_c in {0,1}  -> mq
//  [256,384) : kv partials + k-bit counts, 2 units/block
// =====================================================================
__global__ __launch_bounds__(512) void phaseB_kernel(
    const float* __restrict__ x, const float* __restrict__ Wqk,
    const float* __restrict__ bqk, const float* __restrict__ gamma,
    const float* __restrict__ beta, unsigned* __restrict__ mq,
    unsigned* __restrict__ mk, const float* __restrict__ tbl,
    float* __restrict__ kvp, float* __restrict__ kmp)
{
    __shared__ float smem[12800];
    __shared__ unsigned nib[2048];
    int t = threadIdx.x;
    int blk = blockIdx.x;
    if (blk < 256) {
        gemm_lif_512(x, Wqk, bqk, gamma, beta, mq, mk, smem, nib,
                     blk >> 1, blk & 1, t);
        return;
    }
    // ---- kv partials: 2 independent 256-thr units ----
    int ks2 = t >> 8, tl = t & 255;
    int unit = (blk - 256) * 2 + ks2;      // 0..255
    int bh = unit >> 2, seg = unit & 3;
    int b = bh >> 3, h = bh & 7;
    int n0 = seg * 256;
    float* kr   = smem + ks2 * 4800;       // [64][36]
    float* vhs  = kr + 2304;               // [64][33]
    float* part = kr + 4416;               // [8][32]
    int d = tl & 31, ch = tl >> 5;
    int sc = 0;
    for (int i = 0; i < 32; ++i)
        sc += (mk[bh * 1024 + n0 + ch * 32 + i] >> d) & 1u;
    part[ch * 32 + d] = (float)sc;
    __syncthreads();
    if (tl < 32) {
        float cs = 0.f;
        #pragma unroll
        for (int j = 0; j < 8; ++j) cs += part[j * 32 + tl];
        kmp[bh * 128 + seg * 32 + tl] = cs;
    }
    float a0 = 0, a1 = 0, a2 = 0, a3 = 0;
    int e = tl & 31, db = (tl >> 5) * 4;
    for (int c0 = n0; c0 < n0 + 256; c0 += 64) {
        __syncthreads();
        #pragma unroll
        for (int i = 0; i < 8; ++i) {
            int f = tl + i * 256;
            int nn = f >> 5, dd = f & 31;
            int n = c0 + nn;
            unsigned w = mk[bh * 1024 + n];
            float kd = 1.0f + (float)((w >> dd) & 1u);
            float ko = 1.0f + (float)((w >> (dd ^ 1)) & 1u);
            const float* cp = tbl + n * 256 + h * 32 + (dd & ~1);
            float cc2 = cp[0], ss2 = cp[1];
            kr[nn * 36 + dd] = (dd & 1) ? (ss2 * ko + cc2 * kd) : (cc2 * kd - ss2 * ko);
            vhs[nn * 33 + dd] = x[(b * 1024 + n) * 256 + h * 32 + dd];
        }
        __syncthreads();
        #pragma unroll 8
        for (int nn = 0; nn < 64; ++nn) {
            float ve = vhs[nn * 33 + e];
            float4 kk = *(const float4*)&kr[nn * 36 + db];
            a0 = fmaf(kk.x, ve, a0); a1 = fmaf(kk.y, ve, a1);
            a2 = fmaf(kk.z, ve, a2); a3 = fmaf(kk.w, ve, a3);
        }
    }
    float* dst = kvp + bh * 4096 + seg * 1024;
    dst[(db + 0) * 32 + e] = a0;
    dst[(db + 1) * 32 + e] = a1;
    dst[(db + 2) * 32 + e] = a2;
    dst[(db + 3) * 32 + e] = a3;
}

// =====================================================================
// Phase C (256 thr, 2560 blocks): all heavy writes (PLAIN stores)
//  [0,512)    : out = q_rope@kv * z + lepe
//  [512,2560) : atten + qh/kh regen
// =====================================================================
__global__ __launch_bounds__(256) void phaseC_kernel(
    const unsigned* __restrict__ mq, const unsigned* __restrict__ mk,
    const float* __restrict__ x, const float* __restrict__ tbl,
    const float* __restrict__ kvp, const float* __restrict__ kmp,
    const float* __restrict__ lw, const float* __restrict__ lb,
    float* __restrict__ outbase)
{
    int t = threadIdx.x;
    if (blockIdx.x >= 512) {               // ---- atten + qh/kh ----
        int blk = blockIdx.x - 512;
        int bh = blk >> 5;
        int tile = blk & 31;
        float* qh = outbase + OFF_QH;
        float* kh = outbase + OFF_KH;
        float* att = outbase + OFF_ATT;
        {
            int row = tile * 32 + (t >> 3);
            int d0 = (t & 7) * 4;
            unsigned wq = mq[bh * 1024 + row], wk = mk[bh * 1024 + row];
            f32x4 a, bb;
            a.x = 1.f + (float)((wq >> (d0 + 0)) & 1u);
            a.y = 1.f + (float)((wq >> (d0 + 1)) & 1u);
            a.z = 1.f + (float)((wq >> (d0 + 2)) & 1u);
            a.w = 1.f + (float)((wq >> (d0 + 3)) & 1u);
            bb.x = 1.f + (float)((wk >> (d0 + 0)) & 1u);
            bb.y = 1.f + (float)((wk >> (d0 + 1)) & 1u);
            bb.z = 1.f + (float)((wk >> (d0 + 2)) & 1u);
            bb.w = 1.f + (float)((wk >> (d0 + 3)) & 1u);
            *(f32x4*)&qh[((bh * 1024 + row) << 5) + d0] = a;
            *(f32x4*)&kh[((bh * 1024 + row) << 5) + d0] = bb;
        }
        uint4 mm = ((const uint4*)(mk + bh * 1024))[t];
        float4 rr;
        rr.x = (float)__popc(mm.x); rr.y = (float)__popc(mm.y);
        rr.z = (float)__popc(mm.z); rr.w = (float)__popc(mm.w);
        float* base = att + ((size_t)bh * 1024 + (size_t)tile * 32) * 1024;
        const unsigned* mqrow = mq + bh * 1024 + tile * 32;
        for (int row = 0; row < 32; ++row) {
            unsigned mqw = mqrow[row];
            float rq = 32.0f + (float)__popc(mqw);
            f32x4 o;
            o.x = rq + rr.x + (float)__popc(mqw & mm.x);
            o.y = rq + rr.y + (float)__popc(mqw & mm.y);
            o.z = rq + rr.z + (float)__popc(mqw & mm.z);
            o.w = rq + rr.w + (float)__popc(mqw & mm.w);
            ((f32x4*)(base + (size_t)row * 1024))[t] = o;
        }
        return;
    }
    // ---- out ----
    int bi = blockIdx.x;
    int bh = bi >> 3, sub = bi & 7;
    int pseg = sub >> 1, half = sub & 1;
    int b = bh >> 3, h = bh & 7;
    bool hy = (h < 4);
    int e = t & 31, p_l = t >> 5;
    int p = pseg * 8 + p_l;
    int q0 = half * 16;
    float* out = outbase + OFF_OUT;

    __shared__ float kvs[32][32];
    __shared__ float kmf[32];
    __shared__ float zs[128];
    const float inv = 1.0f / 1024.0f;
    #pragma unroll
    for (int i = 0; i < 4; ++i) {
        int f = t + i * 256;
        const float* kp = kvp + bh * 4096 + f;
        kvs[f >> 5][f & 31] = (kp[0] + kp[1024] + kp[2048] + kp[3072]) * inv;
    }
    if (t < 32) {
        const float* mp = kmp + bh * 128 + t;
        kmf[t] = 1.0f + (mp[0] + mp[32] + mp[64] + mp[96]) * inv;
    }
    __syncthreads();
    float S = 0.f;
    #pragma unroll
    for (int dd = 0; dd < 32; ++dd) S += kmf[dd];
    if (t < 128) {
        int pl2 = t >> 4, iq = t & 15;
        int pp = pseg * 8 + pl2, qq = q0 + iq;
        int n = hy ? (pp * 32 + qq) : (qq * 32 + pp);
        unsigned w = mq[bh * 1024 + n];
        float acc = S;
        #pragma unroll
        for (int dd = 0; dd < 32; ++dd)
            acc += (float)((w >> dd) & 1u) * kmf[dd];
        zs[t] = 1.0f / (acc + 1e-6f);
    }
    int n_ref = hy ? (p * 32) : p;
    const float* cp = tbl + n_ref * 256 + h * 32;
    float E[16], O[16], B = 0.f;
    #pragma unroll
    for (int j = 0; j < 16; ++j) {
        float c2 = cp[2 * j], s2 = cp[2 * j + 1];
        float K0 = kvs[2 * j][e], K1 = kvs[2 * j + 1][e];
        E[j] = c2 * K0 + s2 * K1;
        O[j] = c2 * K1 - s2 * K0;
        B += E[j] + O[j];
    }
    __syncthreads();
    int c = h * 32 + e;
    float w9[9];
    #pragma unroll
    for (int j = 0; j < 9; ++j) w9[j] = lw[c * 9 + j];
    float lbv = lb[c];
    const float* xb = x + (size_t)b * 262144 + c;
    auto ld = [&](int yy, int xx) -> float {
        if ((unsigned)yy > 31u || (unsigned)xx > 31u) return 0.f;
        return xb[(yy * 32 + xx) * 256];
    };
    if (hy) {
        int y = p;
        float Wm0 = ld(y - 1, q0 - 1), Wm1 = ld(y, q0 - 1), Wm2 = ld(y + 1, q0 - 1);
        float Wc0 = ld(y - 1, q0),     Wc1 = ld(y, q0),     Wc2 = ld(y + 1, q0);
        #pragma unroll 4
        for (int i = 0; i < 16; ++i) {
            int m = q0 + i;
            float Wp0 = ld(y - 1, m + 1), Wp1 = ld(y, m + 1), Wp2 = ld(y + 1, m + 1);
            int n = y * 32 + m;
            unsigned w = mq[bh * 1024 + n];
            float o = B;
            #pragma unroll
            for (int j = 0; j < 16; ++j) {
                o += (float)((w >> (2 * j)) & 1u) * E[j];
                o += (float)((w >> (2 * j + 1)) & 1u) * O[j];
            }
            o *= zs[p_l * 16 + i];
            float l = lbv;
            l = fmaf(w9[0], Wm0, l); l = fmaf(w9[1], Wc0, l); l = fmaf(w9[2], Wp0, l);
            l = fmaf(w9[3], Wm1, l); l = fmaf(w9[4], Wc1, l); l = fmaf(w9[5], Wp1, l);
            l = fmaf(w9[6], Wm2, l); l = fmaf(w9[7], Wc2, l); l = fmaf(w9[8], Wp2, l);
            out[((b * 1024 + n) << 8) + c] = o + l;
            Wm0 = Wc0; Wm1 = Wc1; Wm2 = Wc2;
            Wc0 = Wp0; Wc1 = Wp1; Wc2 = Wp2;
        }
    } else {
        int xx0 = p;
        float Wm0 = ld(q0 - 1, xx0 - 1), Wm1 = ld(q0 - 1, xx0), Wm2 = ld(q0 - 1, xx0 + 1);
        float Wc0 = ld(q0, xx0 - 1),     Wc1 = ld(q0, xx0),     Wc2 = ld(q0, xx0 + 1);
        #pragma unroll 4
        for (int i = 0; i < 16; ++i) {
            int m = q0 + i;
            float Wp0 = ld(m + 1, xx0 - 1), Wp1 = ld(m + 1, xx0), Wp2 = ld(m + 1, xx0 + 1);
            int n = m * 32 + xx0;
            unsigned w = mq[bh * 1024 + n];
            float o = B;
            #pragma unroll
            for (int j = 0; j < 16; ++j) {
                o += (float)((w >> (2 * j)) & 1u) * E[j];
                o += (float)((w >> (2 * j + 1)) & 1u) * O[j];
            }
            o *= zs[p_l * 16 + i];
            float l = lbv;
            l = fmaf(w9[0], Wm0, l); l = fmaf(w9[1], Wm1, l); l = fmaf(w9[2], Wm2, l);
            l = fmaf(w9[3], Wc0, l); l = fmaf(w9[4], Wc1, l); l = fmaf(w9[5], Wc2, l);
            l = fmaf(w9[6], Wp0, l); l = fmaf(w9[7], Wp1, l); l = fmaf(w9[8], Wp2, l);
            out[((b * 1024 + n) << 8) + c] = o + l;
            Wm0 = Wc0; Wm1 = Wc1; Wm2 = Wc2;
            Wc0 = Wp0; Wc1 = Wp1; Wc2 = Wp2;
        }
    }
}

extern "C" void kernel_launch(void* const* d_in, const int* in_sizes, int n_in,
                              void* d_out, int out_size, void* d_ws, size_t ws_size,
                              hipStream_t stream)
{
    const float* x     = (const float*)d_in[0];
    const float* Wqk   = (const float*)d_in[1];
    const float* bqk   = (const float*)d_in[2];
    const float* gamma = (const float*)d_in[3];
    const float* beta  = (const float*)d_in[4];
    const float* lw    = (const float*)d_in[5];
    const float* lb    = (const float*)d_in[6];
    float* out = (float*)d_out;
    unsigned* ws = (unsigned*)d_ws;
    unsigned* mq = ws + WS_MQ;
    unsigned* mk = ws + WS_MK;
    float* tbl  = (float*)(ws + WS_TBL);
    float* kvp  = (float*)(ws + WS_KVP);
    float* kmp  = (float*)(ws + WS_KMP);

    hipLaunchKernelGGL(phaseA_kernel, dim3(1536), dim3(512), 0, stream,
                       x, Wqk, bqk, gamma, beta, mq, mk, out + OFF_VIMG, tbl);
    hipLaunchKernelGGL(phaseB_kernel, dim3(384), dim3(512), 0, stream,
                       x, Wqk, bqk, gamma, beta, mq, mk, tbl, kvp, kmp);
    hipLaunchKernelGGL(phaseC_kernel, dim3(2560), dim3(256), 0, stream,
                       mq, mk, x, tbl, kvp, kmp, lw, lb, out);
}